// Round 5
// baseline (394.699 us; speedup 1.0000x reference)
//
#include <hip/hip_runtime.h>
#include <math.h>

#define DD 128
#define NEG 0.01f
#define SCHUNK 4096

typedef __attribute__((ext_vector_type(8))) short short8;
typedef __attribute__((ext_vector_type(4))) float f32x4;

__device__ __forceinline__ float lrelu(float x){ return x > 0.f ? x : NEG * x; }

// fp32 -> bf16 round-to-nearest-even (finite inputs)
__device__ __forceinline__ unsigned short f2bf(float f){
    unsigned u = __float_as_uint(f);
    u += 0x7fffu + ((u >> 16) & 1u);
    return (unsigned short)(u >> 16);
}
__device__ __forceinline__ float bf2f(unsigned short h){
    return __uint_as_float(((unsigned)h) << 16);
}

__global__ void init_deg(int* deg, int n_dst){
    int i = blockIdx.x * blockDim.x + threadIdx.x;
    if (i < n_dst) deg[i] = 0;
}

__global__ void hist_kernel(const int* dst, int* deg, int E){
    int i = blockIdx.x * blockDim.x + threadIdx.x;
    if (i < E) atomicAdd(&deg[dst[i]], 1);
}

// two-level scan, level 1: per-chunk sums (chunk = 4096 ints)
__global__ __launch_bounds__(1024) void scan1(const int* deg, int* part, int n){
    __shared__ int wsum[16];
    const int tid = threadIdx.x;
    const int lane = tid & 63, wid = tid >> 6;
    int i4 = blockIdx.x * SCHUNK + tid * 4;
    int4 v = make_int4(0, 0, 0, 0);
    if (i4 + 3 < n) v = *(const int4*)(deg + i4);
    else {
        if (i4 + 0 < n) v.x = deg[i4 + 0];
        if (i4 + 1 < n) v.y = deg[i4 + 1];
        if (i4 + 2 < n) v.z = deg[i4 + 2];
        if (i4 + 3 < n) v.w = deg[i4 + 3];
    }
    int t = v.x + v.y + v.z + v.w;
    #pragma unroll
    for (int off = 1; off < 64; off <<= 1) t += __shfl_xor(t, off, 64);
    if (lane == 0) wsum[wid] = t;
    __syncthreads();
    if (tid == 0){
        int s = 0;
        #pragma unroll
        for (int j = 0; j < 16; j++) s += wsum[j];
        part[blockIdx.x] = s;
    }
}

// two-level scan, level 2: exclusive offsets + cursor copy
__global__ __launch_bounds__(1024) void scan2(const int* deg, const int* part,
        int* row_off, int* cursor, int n, int nchunks){
    __shared__ int wsum[16];
    const int tid = threadIdx.x;
    const int lane = tid & 63, wid = tid >> 6;
    const int b = blockIdx.x;
    int carry = 0;
    for (int j = 0; j < b; j++) carry += part[j];
    int i4 = b * SCHUNK + tid * 4;
    int4 v = make_int4(0, 0, 0, 0);
    if (i4 + 3 < n) v = *(const int4*)(deg + i4);
    else {
        if (i4 + 0 < n) v.x = deg[i4 + 0];
        if (i4 + 1 < n) v.y = deg[i4 + 1];
        if (i4 + 2 < n) v.z = deg[i4 + 2];
        if (i4 + 3 < n) v.w = deg[i4 + 3];
    }
    int tsum = v.x + v.y + v.z + v.w;
    int x = tsum;
    #pragma unroll
    for (int off = 1; off < 64; off <<= 1){
        int t = __shfl_up(x, off, 64);
        if (lane >= off) x += t;
    }
    if (lane == 63) wsum[wid] = x;
    __syncthreads();
    int wprefix = 0;
    #pragma unroll
    for (int j = 0; j < 16; j++) if (j < wid) wprefix += wsum[j];
    int excl = carry + wprefix + (x - tsum);
    if (i4 + 3 < n){
        int4 o;
        o.x = excl; o.y = excl + v.x; o.z = o.y + v.y; o.w = o.z + v.z;
        *(int4*)(row_off + i4) = o;
        *(int4*)(cursor + i4) = o;
    } else {
        int a = excl;
        if (i4 + 0 < n){ row_off[i4 + 0] = a; cursor[i4 + 0] = a; a += v.x; }
        if (i4 + 1 < n){ row_off[i4 + 1] = a; cursor[i4 + 1] = a; a += v.y; }
        if (i4 + 2 < n){ row_off[i4 + 2] = a; cursor[i4 + 2] = a; a += v.z; }
        if (i4 + 3 < n){ row_off[i4 + 3] = a; cursor[i4 + 3] = a; }
    }
    if (b == 0 && tid == 0){
        int tot = 0;
        for (int j = 0; j < nchunks; j++) tot += part[j];
        row_off[n] = tot;
    }
}

// bucket edges by dst: sorted (src,dst) pairs in CSR order
__global__ void scatter_pairs(const int* src, const int* dst, int* cursor,
                              int2* pairs, int E){
    int i = blockIdx.x * blockDim.x + threadIdx.x;
    if (i < E){
        int d = dst[i];
        int pos = atomicAdd(&cursor[d], 1);
        pairs[pos] = make_int2(src[i], d);
    }
}

// pack 4 weight matrices into bf16 MFMA B-fragment-linear order.
// seg 0: Wa1 hi; 1,2: Wsrc hi,lo; 3,4: Wdst hi,lo; 5,6: Wout hi,lo
__global__ void pack_weights(const float* Wa1, const float* Wsrc,
                             const float* Wdst, const float* Wout,
                             unsigned short* out){
    int i = blockIdx.x * blockDim.x + threadIdx.x;   // 7*16384
    if (i >= 7 * 16384) return;
    int seg = i >> 14, t = i & 16383;
    int j = t & 7, lane = (t >> 3) & 63, nt = (t >> 9) & 7, kc = t >> 12;
    int k = kc * 32 + (lane >> 4) * 8 + j;
    int n = nt * 16 + (lane & 15);
    const float* W = (seg == 0) ? Wa1 : (seg <= 2) ? Wsrc : (seg <= 4) ? Wdst : Wout;
    float w = W[k * DD + n];
    unsigned short hi = f2bf(w);
    unsigned short val = hi;
    if (seg == 2 || seg == 4 || seg == 6) val = f2bf(w - bf2f(hi));
    out[i] = val;
}

// Node linear via MFMA, bf16 hi/lo split (~fp32 accuracy).
// Y[r] = act(X[r] @ W + b). 128 rows/block (4 waves x 32 rows).
__global__ __launch_bounds__(256) void lin_mfma(const float* X,
        const unsigned short* Whi, const unsigned short* Wlo, const float* b,
        float* Y, unsigned short* Yb, int nrows, int do_act){
    __shared__ unsigned short sB[2][16384];   // 64 KB
    const int tid = threadIdx.x;
    {
        const uint4* gh = (const uint4*)Whi;
        const uint4* gl = (const uint4*)Wlo;
        uint4* lh = (uint4*)sB[0];
        uint4* ll = (uint4*)sB[1];
        #pragma unroll
        for (int t = 0; t < 8; t++){
            lh[tid + 256 * t] = gh[tid + 256 * t];
            ll[tid + 256 * t] = gl[tid + 256 * t];
        }
    }
    const int wave = tid >> 6, lane = tid & 63;
    const int qd = lane >> 4, ln16 = lane & 15;
    const int row0 = blockIdx.x * 128 + wave * 32;
    int r0 = row0 + ln16;       if (r0 >= nrows) r0 = nrows - 1;
    int r1 = row0 + 16 + ln16;  if (r1 >= nrows) r1 = nrows - 1;
    f32x4 acc[2][8];
    #pragma unroll
    for (int rt = 0; rt < 2; rt++)
        #pragma unroll
        for (int nt = 0; nt < 8; nt++)
            acc[rt][nt] = (f32x4){0.f, 0.f, 0.f, 0.f};
    __syncthreads();
    #pragma unroll
    for (int kc = 0; kc < 4; kc++){
        const int koff = kc * 32 + qd * 8;
        short8 ahi[2], alo[2];
        const float* px[2] = {X + (size_t)r0 * DD + koff, X + (size_t)r1 * DD + koff};
        #pragma unroll
        for (int rt = 0; rt < 2; rt++){
            float4 v0 = *(const float4*)(px[rt]);
            float4 v1 = *(const float4*)(px[rt] + 4);
            float xv[8] = {v0.x, v0.y, v0.z, v0.w, v1.x, v1.y, v1.z, v1.w};
            #pragma unroll
            for (int j = 0; j < 8; j++){
                unsigned short h = f2bf(xv[j]);
                ahi[rt][j] = (short)h;
                alo[rt][j] = (short)f2bf(xv[j] - bf2f(h));
            }
        }
        #pragma unroll
        for (int nt = 0; nt < 8; nt++){
            const int fi = (((kc << 3) + nt) << 6 | lane) << 3;
            short8 bh = *(const short8*)&sB[0][fi];
            short8 bl = *(const short8*)&sB[1][fi];
            #pragma unroll
            for (int rt = 0; rt < 2; rt++){
                acc[rt][nt] = __builtin_amdgcn_mfma_f32_16x16x32_bf16(ahi[rt], bh, acc[rt][nt], 0, 0, 0);
                acc[rt][nt] = __builtin_amdgcn_mfma_f32_16x16x32_bf16(alo[rt], bh, acc[rt][nt], 0, 0, 0);
                acc[rt][nt] = __builtin_amdgcn_mfma_f32_16x16x32_bf16(ahi[rt], bl, acc[rt][nt], 0, 0, 0);
            }
        }
    }
    #pragma unroll
    for (int nt = 0; nt < 8; nt++){
        const int col = nt * 16 + ln16;
        const float bv = b[col];
        #pragma unroll
        for (int rt = 0; rt < 2; rt++){
            #pragma unroll
            for (int r = 0; r < 4; r++){
                int row = row0 + rt * 16 + qd * 4 + r;
                if (row < nrows){
                    float y = acc[rt][nt][r] + bv;
                    if (do_act) y = lrelu(y);
                    if (Y) Y[(size_t)row * DD + col] = y;
                    if (Yb) Yb[(size_t)row * DD + col] = f2bf(y);
                }
            }
        }
    }
}

// build A-fragment: 8 bf16 of lrelu(hs_row + hd_row)
__device__ __forceinline__ short8 make_afrag(const unsigned short* ph, const unsigned short* pd){
    uint4 a = *(const uint4*)ph;
    uint4 b = *(const uint4*)pd;
    unsigned au[4] = {a.x, a.y, a.z, a.w};
    unsigned bu[4] = {b.x, b.y, b.z, b.w};
    short8 r;
    #pragma unroll
    for (int i = 0; i < 4; i++){
        float h0 = __uint_as_float(au[i] << 16);
        float h1 = __uint_as_float(au[i] & 0xffff0000u);
        float g0 = __uint_as_float(bu[i] << 16);
        float g1 = __uint_as_float(bu[i] & 0xffff0000u);
        float e0 = lrelu(h0 + g0);
        float e1 = lrelu(h1 + g1);
        r[2 * i]     = (short)f2bf(e0);
        r[2 * i + 1] = (short)f2bf(e1);
    }
    return r;
}

// MFMA edge attention score on SORTED edges; linear score write.
// Grid-stride over 128-edge tiles; LDS weight stage amortized.
__global__ __launch_bounds__(256) void edge_score_mfma(
        const unsigned short* hs_b, const unsigned short* hd_b,
        const int2* pairs,
        const unsigned short* wa1p, const float* ba1,
        const float* Wa2, const float* ba2,
        float* s_score, int E, int ntiles){
    __shared__ unsigned short sB[16384];  // 32 KB
    const int tid = threadIdx.x;
    {
        const uint4* g = (const uint4*)wa1p;
        uint4* l = (uint4*)sB;
        #pragma unroll
        for (int t = 0; t < 8; t++) l[tid + 256 * t] = g[tid + 256 * t];
    }
    const int wave = tid >> 6, lane = tid & 63;
    const int qd = lane >> 4, ln16 = lane & 15;
    float b1v[8], w2v[8];
    #pragma unroll
    for (int nt = 0; nt < 8; nt++){
        b1v[nt] = ba1[nt * 16 + ln16];
        w2v[nt] = Wa2[nt * 16 + ln16];
    }
    const float b2 = ba2[0];
    __syncthreads();
    for (int tile = blockIdx.x; tile < ntiles; tile += gridDim.x){
        const int e0 = tile * 128 + wave * 32;
        int eid0 = e0 + ln16;       if (eid0 >= E) eid0 = E - 1;
        int eid1 = e0 + 16 + ln16;  if (eid1 >= E) eid1 = E - 1;
        const int2 p0 = pairs[eid0];
        const int2 p1 = pairs[eid1];
        f32x4 acc[2][8];
        #pragma unroll
        for (int rt = 0; rt < 2; rt++)
            #pragma unroll
            for (int nt = 0; nt < 8; nt++)
                acc[rt][nt] = (f32x4){0.f, 0.f, 0.f, 0.f};
        #pragma unroll
        for (int kc = 0; kc < 4; kc++){
            const int koff = kc * 32 + qd * 8;
            short8 af0 = make_afrag(hs_b + (size_t)p0.x * DD + koff, hd_b + (size_t)p0.y * DD + koff);
            short8 af1 = make_afrag(hs_b + (size_t)p1.x * DD + koff, hd_b + (size_t)p1.y * DD + koff);
            #pragma unroll
            for (int nt = 0; nt < 8; nt++){
                short8 bf = *(const short8*)&sB[(((kc << 3) + nt) << 6 | lane) << 3];
                acc[0][nt] = __builtin_amdgcn_mfma_f32_16x16x32_bf16(af0, bf, acc[0][nt], 0, 0, 0);
                acc[1][nt] = __builtin_amdgcn_mfma_f32_16x16x32_bf16(af1, bf, acc[1][nt], 0, 0, 0);
            }
        }
        #pragma unroll
        for (int rt = 0; rt < 2; rt++){
            float p[4] = {0.f, 0.f, 0.f, 0.f};
            #pragma unroll
            for (int nt = 0; nt < 8; nt++)
                #pragma unroll
                for (int r = 0; r < 4; r++){
                    float z = acc[rt][nt][r] + b1v[nt];
                    z = z > 0.f ? z : NEG * z;
                    p[r] += z * w2v[nt];
                }
            #pragma unroll
            for (int r = 0; r < 4; r++){
                float v = p[r];
                #pragma unroll
                for (int off = 1; off < 16; off <<= 1) v += __shfl_xor(v, off, 64);
                p[r] = v;
            }
            if (ln16 == 0){
                int row = e0 + rt * 16 + qd * 4;
                #pragma unroll
                for (int r = 0; r < 4; r++)
                    if (row + r < E) s_score[row + r] = p[r] + b2;
            }
        }
    }
}

// one wave per dst node: softmax over its CSR segment + weighted bf16 gather.
// nf[n] = sum_e alpha_e * hs[src_e] + (sum_e alpha_e) * hd[n]
__global__ __launch_bounds__(256) void agg_softmax(const unsigned short* hs_b,
        const float* hd, const int* row_off, const int2* pairs,
        const float* s_score, float* nf, int n_dst){
    const int w = (blockIdx.x * blockDim.x + threadIdx.x) >> 6;
    const int lane = threadIdx.x & 63;
    if (w >= n_dst) return;
    const int beg = row_off[w], end = row_off[w + 1];
    float m = -INFINITY;
    for (int e = beg + lane; e < end; e += 64) m = fmaxf(m, s_score[e]);
    #pragma unroll
    for (int off = 1; off < 64; off <<= 1) m = fmaxf(m, __shfl_xor(m, off, 64));
    float sm = 0.f;
    for (int e = beg + lane; e < end; e += 64) sm += expf(s_score[e] - m);
    #pragma unroll
    for (int off = 1; off < 64; off <<= 1) sm += __shfl_xor(sm, off, 64);
    const float inv = (end > beg) ? 1.f / sm : 0.f;
    float2 acc = make_float2(0.f, 0.f);
    float sa = 0.f;
    int e = beg;
    for (; e + 1 < end; e += 2){
        float a0 = expf(s_score[e] - m) * inv;
        float a1 = expf(s_score[e + 1] - m) * inv;
        int s0 = pairs[e].x, s1 = pairs[e + 1].x;
        ushort2 u0 = *(const ushort2*)(hs_b + (size_t)s0 * DD + lane * 2);
        ushort2 u1 = *(const ushort2*)(hs_b + (size_t)s1 * DD + lane * 2);
        acc.x += a0 * bf2f(u0.x) + a1 * bf2f(u1.x);
        acc.y += a0 * bf2f(u0.y) + a1 * bf2f(u1.y);
        sa += a0 + a1;
    }
    if (e < end){
        float a0 = expf(s_score[e] - m) * inv;
        int s0 = pairs[e].x;
        ushort2 u0 = *(const ushort2*)(hs_b + (size_t)s0 * DD + lane * 2);
        acc.x += a0 * bf2f(u0.x);
        acc.y += a0 * bf2f(u0.y);
        sa += a0;
    }
    float2 h = *(const float2*)(hd + (size_t)w * DD + lane * 2);
    float2 out;
    out.x = acc.x + sa * h.x;
    out.y = acc.y + sa * h.y;
    *(float2*)(nf + (size_t)w * DD + lane * 2) = out;
}

extern "C" void kernel_launch(void* const* d_in, const int* in_sizes, int n_in,
                              void* d_out, int out_size, void* d_ws, size_t ws_size,
                              hipStream_t stream){
    const float* feat_src = (const float*)d_in[0];
    const float* feat_dst = (const float*)d_in[1];
    const int*   src_idx  = (const int*)d_in[2];
    const int*   dst_idx  = (const int*)d_in[3];
    const float* W_src = (const float*)d_in[4];
    const float* b_src = (const float*)d_in[5];
    const float* W_dst = (const float*)d_in[6];
    const float* b_dst = (const float*)d_in[7];
    const float* W_a1  = (const float*)d_in[8];
    const float* b_a1  = (const float*)d_in[9];
    const float* W_a2  = (const float*)d_in[10];
    const float* b_a2  = (const float*)d_in[11];
    const float* W_out = (const float*)d_in[12];
    const float* b_out = (const float*)d_in[13];
    const int n_src = in_sizes[0] / DD;
    const int n_dst = in_sizes[1] / DD;
    const int E = in_sizes[2];
    const int nchunks = (n_dst + SCHUNK - 1) / SCHUNK;
    const int ntiles = (E + 127) / 128;

    // workspace layout (all 16B-aligned segments)
    char* p = (char*)d_ws;
    float* hd = (float*)p;                      p += (size_t)n_dst * DD * 4;
    unsigned short* hs_b = (unsigned short*)p;  p += (size_t)n_src * DD * 2;
    unsigned short* hd_b = (unsigned short*)p;  p += (size_t)n_dst * DD * 2;
    unsigned short* wpack = (unsigned short*)p; p += 7 * 16384 * 2;
    float* s_score = (float*)p;                 p += (size_t)E * 4;
    int2* pairs = (int2*)p;                     p += (size_t)E * 8;
    int* deg = (int*)p;                         p += (size_t)n_dst * 4;
    int* cursor = (int*)p;                      p += (size_t)n_dst * 4;
    int* part = (int*)p;                        p += 64 * 4;
    int* row_off = (int*)p;                     p += ((size_t)n_dst + 1) * 4;
    float* nf = (float*)d_out;

    const unsigned short* wa1p    = wpack;
    const unsigned short* wsrc_hi = wpack + 1 * 16384;
    const unsigned short* wsrc_lo = wpack + 2 * 16384;
    const unsigned short* wdst_hi = wpack + 3 * 16384;
    const unsigned short* wdst_lo = wpack + 4 * 16384;
    const unsigned short* wout_hi = wpack + 5 * 16384;
    const unsigned short* wout_lo = wpack + 6 * 16384;

    init_deg<<<(n_dst + 255) / 256, 256, 0, stream>>>(deg, n_dst);
    hist_kernel<<<(E + 255) / 256, 256, 0, stream>>>(dst_idx, deg, E);
    scan1<<<nchunks, 1024, 0, stream>>>(deg, part, n_dst);
    scan2<<<nchunks, 1024, 0, stream>>>(deg, part, row_off, cursor, n_dst, nchunks);
    pack_weights<<<(7 * 16384 + 255) / 256, 256, 0, stream>>>(W_a1, W_src, W_dst, W_out, wpack);
    scatter_pairs<<<(E + 255) / 256, 256, 0, stream>>>(src_idx, dst_idx, cursor, pairs, E);
    lin_mfma<<<(n_src + 127) / 128, 256, 0, stream>>>(feat_src, wsrc_hi, wsrc_lo, b_src,
                                                      (float*)nullptr, hs_b, n_src, 0);
    lin_mfma<<<(n_dst + 127) / 128, 256, 0, stream>>>(feat_dst, wdst_hi, wdst_lo, b_dst,
                                                      hd, hd_b, n_dst, 0);
    int esgrid = ntiles < 1024 ? ntiles : 1024;
    edge_score_mfma<<<esgrid, 256, 0, stream>>>(hs_b, hd_b, pairs, wa1p, b_a1,
                                                W_a2, b_a2, s_score, E, ntiles);
    agg_softmax<<<((size_t)n_dst * 64 + 255) / 256, 256, 0, stream>>>(hs_b, hd, row_off,
                                                                      pairs, s_score, nf, n_dst);
    lin_mfma<<<(n_dst + 127) / 128, 256, 0, stream>>>(nf, wout_hi, wout_lo, b_out,
                                                      nf, (unsigned short*)nullptr, n_dst, 1);
}

// Round 6
// 354.754 us; speedup vs baseline: 1.1126x; 1.1126x over previous
//
#include <hip/hip_runtime.h>
#include <math.h>

#define DD 128
#define NEG 0.01f
#define SCHUNK 4096

typedef __attribute__((ext_vector_type(8))) short short8;
typedef __attribute__((ext_vector_type(4))) float f32x4;

__device__ __forceinline__ float lrelu(float x){ return x > 0.f ? x : NEG * x; }

// fp32 -> bf16 round-to-nearest-even (finite inputs)
__device__ __forceinline__ unsigned short f2bf(float f){
    unsigned u = __float_as_uint(f);
    u += 0x7fffu + ((u >> 16) & 1u);
    return (unsigned short)(u >> 16);
}
__device__ __forceinline__ float bf2f(unsigned short h){
    return __uint_as_float(((unsigned)h) << 16);
}

__global__ void init_deg(int* deg, int n_dst){
    int i = blockIdx.x * blockDim.x + threadIdx.x;
    if (i < n_dst) deg[i] = 0;
}

__global__ void hist_kernel(const int* dst, int* deg, int E){
    int i = blockIdx.x * blockDim.x + threadIdx.x;
    if (i < E) atomicAdd(&deg[dst[i]], 1);
}

// two-level scan, level 1: per-chunk sums (chunk = 4096 ints)
__global__ __launch_bounds__(1024) void scan1(const int* deg, int* part, int n){
    __shared__ int wsum[16];
    const int tid = threadIdx.x;
    const int lane = tid & 63, wid = tid >> 6;
    int i4 = blockIdx.x * SCHUNK + tid * 4;
    int4 v = make_int4(0, 0, 0, 0);
    if (i4 + 3 < n) v = *(const int4*)(deg + i4);
    else {
        if (i4 + 0 < n) v.x = deg[i4 + 0];
        if (i4 + 1 < n) v.y = deg[i4 + 1];
        if (i4 + 2 < n) v.z = deg[i4 + 2];
        if (i4 + 3 < n) v.w = deg[i4 + 3];
    }
    int t = v.x + v.y + v.z + v.w;
    #pragma unroll
    for (int off = 1; off < 64; off <<= 1) t += __shfl_xor(t, off, 64);
    if (lane == 0) wsum[wid] = t;
    __syncthreads();
    if (tid == 0){
        int s = 0;
        #pragma unroll
        for (int j = 0; j < 16; j++) s += wsum[j];
        part[blockIdx.x] = s;
    }
}

// two-level scan, level 2: exclusive offsets + cursor copy
__global__ __launch_bounds__(1024) void scan2(const int* deg, const int* part,
        int* row_off, int* cursor, int n, int nchunks){
    __shared__ int wsum[16];
    const int tid = threadIdx.x;
    const int lane = tid & 63, wid = tid >> 6;
    const int b = blockIdx.x;
    int carry = 0;
    for (int j = 0; j < b; j++) carry += part[j];
    int i4 = b * SCHUNK + tid * 4;
    int4 v = make_int4(0, 0, 0, 0);
    if (i4 + 3 < n) v = *(const int4*)(deg + i4);
    else {
        if (i4 + 0 < n) v.x = deg[i4 + 0];
        if (i4 + 1 < n) v.y = deg[i4 + 1];
        if (i4 + 2 < n) v.z = deg[i4 + 2];
        if (i4 + 3 < n) v.w = deg[i4 + 3];
    }
    int tsum = v.x + v.y + v.z + v.w;
    int x = tsum;
    #pragma unroll
    for (int off = 1; off < 64; off <<= 1){
        int t = __shfl_up(x, off, 64);
        if (lane >= off) x += t;
    }
    if (lane == 63) wsum[wid] = x;
    __syncthreads();
    int wprefix = 0;
    #pragma unroll
    for (int j = 0; j < 16; j++) if (j < wid) wprefix += wsum[j];
    int excl = carry + wprefix + (x - tsum);
    if (i4 + 3 < n){
        int4 o;
        o.x = excl; o.y = excl + v.x; o.z = o.y + v.y; o.w = o.z + v.z;
        *(int4*)(row_off + i4) = o;
        *(int4*)(cursor + i4) = o;
    } else {
        int a = excl;
        if (i4 + 0 < n){ row_off[i4 + 0] = a; cursor[i4 + 0] = a; a += v.x; }
        if (i4 + 1 < n){ row_off[i4 + 1] = a; cursor[i4 + 1] = a; a += v.y; }
        if (i4 + 2 < n){ row_off[i4 + 2] = a; cursor[i4 + 2] = a; a += v.z; }
        if (i4 + 3 < n){ row_off[i4 + 3] = a; cursor[i4 + 3] = a; }
    }
    if (b == 0 && tid == 0){
        int tot = 0;
        for (int j = 0; j < nchunks; j++) tot += part[j];
        row_off[n] = tot;
    }
}

// bucket edges by dst: sorted (src,dst) pairs in CSR order + SoA src copy
__global__ void scatter_pairs(const int* src, const int* dst, int* cursor,
                              int2* pairs, int* s_srcs, int E){
    int i = blockIdx.x * blockDim.x + threadIdx.x;
    if (i < E){
        int d = dst[i];
        int s = src[i];
        int pos = atomicAdd(&cursor[d], 1);
        pairs[pos] = make_int2(s, d);
        s_srcs[pos] = s;
    }
}

// pack 4 weight matrices into bf16 MFMA B-fragment-linear order.
// seg 0: Wa1 hi; 1,2: Wsrc hi,lo; 3,4: Wdst hi,lo; 5,6: Wout hi,lo
__global__ void pack_weights(const float* Wa1, const float* Wsrc,
                             const float* Wdst, const float* Wout,
                             unsigned short* out){
    int i = blockIdx.x * blockDim.x + threadIdx.x;   // 7*16384
    if (i >= 7 * 16384) return;
    int seg = i >> 14, t = i & 16383;
    int j = t & 7, lane = (t >> 3) & 63, nt = (t >> 9) & 7, kc = t >> 12;
    int k = kc * 32 + (lane >> 4) * 8 + j;
    int n = nt * 16 + (lane & 15);
    const float* W = (seg == 0) ? Wa1 : (seg <= 2) ? Wsrc : (seg <= 4) ? Wdst : Wout;
    float w = W[k * DD + n];
    unsigned short hi = f2bf(w);
    unsigned short val = hi;
    if (seg == 2 || seg == 4 || seg == 6) val = f2bf(w - bf2f(hi));
    out[i] = val;
}

// Node linear via MFMA, bf16 hi/lo split (~fp32 accuracy).
// Y[r] = act(X[r] @ W + b). 128 rows/block (4 waves x 32 rows).
// Fused variant: blocks [0,g1) process (X1,W1,b1)->Yb1; blocks [g1,..) process
// (X2,W2,b2)->Y2,Yb2.
__global__ __launch_bounds__(256) void lin2_mfma(
        const float* X1, const unsigned short* W1hi, const unsigned short* W1lo,
        const float* b1, unsigned short* Yb1, int n1, int g1,
        const float* X2, const unsigned short* W2hi, const unsigned short* W2lo,
        const float* b2, float* Y2, unsigned short* Yb2, int n2){
    __shared__ unsigned short sB[2][16384];   // 64 KB
    const int tid = threadIdx.x;
    const int second = (blockIdx.x >= g1);
    const float* X = second ? X2 : X1;
    const unsigned short* Whi = second ? W2hi : W1hi;
    const unsigned short* Wlo = second ? W2lo : W1lo;
    const float* b = second ? b2 : b1;
    float* Y = second ? Y2 : (float*)nullptr;
    unsigned short* Yb = second ? Yb2 : Yb1;
    const int nrows = second ? n2 : n1;
    const int bidx = second ? (blockIdx.x - g1) : blockIdx.x;
    {
        const uint4* gh = (const uint4*)Whi;
        const uint4* gl = (const uint4*)Wlo;
        uint4* lh = (uint4*)sB[0];
        uint4* ll = (uint4*)sB[1];
        #pragma unroll
        for (int t = 0; t < 8; t++){
            lh[tid + 256 * t] = gh[tid + 256 * t];
            ll[tid + 256 * t] = gl[tid + 256 * t];
        }
    }
    const int wave = tid >> 6, lane = tid & 63;
    const int qd = lane >> 4, ln16 = lane & 15;
    const int row0 = bidx * 128 + wave * 32;
    int r0 = row0 + ln16;       if (r0 >= nrows) r0 = nrows - 1;
    int r1 = row0 + 16 + ln16;  if (r1 >= nrows) r1 = nrows - 1;
    f32x4 acc[2][8];
    #pragma unroll
    for (int rt = 0; rt < 2; rt++)
        #pragma unroll
        for (int nt = 0; nt < 8; nt++)
            acc[rt][nt] = (f32x4){0.f, 0.f, 0.f, 0.f};
    __syncthreads();
    #pragma unroll
    for (int kc = 0; kc < 4; kc++){
        const int koff = kc * 32 + qd * 8;
        short8 ahi[2], alo[2];
        const float* px[2] = {X + (size_t)r0 * DD + koff, X + (size_t)r1 * DD + koff};
        #pragma unroll
        for (int rt = 0; rt < 2; rt++){
            float4 v0 = *(const float4*)(px[rt]);
            float4 v1 = *(const float4*)(px[rt] + 4);
            float xv[8] = {v0.x, v0.y, v0.z, v0.w, v1.x, v1.y, v1.z, v1.w};
            #pragma unroll
            for (int j = 0; j < 8; j++){
                unsigned short h = f2bf(xv[j]);
                ahi[rt][j] = (short)h;
                alo[rt][j] = (short)f2bf(xv[j] - bf2f(h));
            }
        }
        #pragma unroll
        for (int nt = 0; nt < 8; nt++){
            const int fi = (((kc << 3) + nt) << 6 | lane) << 3;
            short8 bh = *(const short8*)&sB[0][fi];
            short8 bl = *(const short8*)&sB[1][fi];
            #pragma unroll
            for (int rt = 0; rt < 2; rt++){
                acc[rt][nt] = __builtin_amdgcn_mfma_f32_16x16x32_bf16(ahi[rt], bh, acc[rt][nt], 0, 0, 0);
                acc[rt][nt] = __builtin_amdgcn_mfma_f32_16x16x32_bf16(alo[rt], bh, acc[rt][nt], 0, 0, 0);
                acc[rt][nt] = __builtin_amdgcn_mfma_f32_16x16x32_bf16(ahi[rt], bl, acc[rt][nt], 0, 0, 0);
            }
        }
    }
    #pragma unroll
    for (int nt = 0; nt < 8; nt++){
        const int col = nt * 16 + ln16;
        const float bv = b[col];
        #pragma unroll
        for (int rt = 0; rt < 2; rt++){
            #pragma unroll
            for (int r = 0; r < 4; r++){
                int row = row0 + rt * 16 + qd * 4 + r;
                if (row < nrows){
                    float y = acc[rt][nt][r] + bv;
                    if (Y) Y[(size_t)row * DD + col] = y;
                    if (Yb) Yb[(size_t)row * DD + col] = f2bf(y);
                }
            }
        }
    }
}

// Final linear (in-place capable): Y = lrelu(X @ W + b)
__global__ __launch_bounds__(256) void lin_mfma(const float* X,
        const unsigned short* Whi, const unsigned short* Wlo, const float* b,
        float* Y, int nrows){
    __shared__ unsigned short sB[2][16384];
    const int tid = threadIdx.x;
    {
        const uint4* gh = (const uint4*)Whi;
        const uint4* gl = (const uint4*)Wlo;
        uint4* lh = (uint4*)sB[0];
        uint4* ll = (uint4*)sB[1];
        #pragma unroll
        for (int t = 0; t < 8; t++){
            lh[tid + 256 * t] = gh[tid + 256 * t];
            ll[tid + 256 * t] = gl[tid + 256 * t];
        }
    }
    const int wave = tid >> 6, lane = tid & 63;
    const int qd = lane >> 4, ln16 = lane & 15;
    const int row0 = blockIdx.x * 128 + wave * 32;
    int r0 = row0 + ln16;       if (r0 >= nrows) r0 = nrows - 1;
    int r1 = row0 + 16 + ln16;  if (r1 >= nrows) r1 = nrows - 1;
    f32x4 acc[2][8];
    #pragma unroll
    for (int rt = 0; rt < 2; rt++)
        #pragma unroll
        for (int nt = 0; nt < 8; nt++)
            acc[rt][nt] = (f32x4){0.f, 0.f, 0.f, 0.f};
    __syncthreads();
    #pragma unroll
    for (int kc = 0; kc < 4; kc++){
        const int koff = kc * 32 + qd * 8;
        short8 ahi[2], alo[2];
        const float* px[2] = {X + (size_t)r0 * DD + koff, X + (size_t)r1 * DD + koff};
        #pragma unroll
        for (int rt = 0; rt < 2; rt++){
            float4 v0 = *(const float4*)(px[rt]);
            float4 v1 = *(const float4*)(px[rt] + 4);
            float xv[8] = {v0.x, v0.y, v0.z, v0.w, v1.x, v1.y, v1.z, v1.w};
            #pragma unroll
            for (int j = 0; j < 8; j++){
                unsigned short h = f2bf(xv[j]);
                ahi[rt][j] = (short)h;
                alo[rt][j] = (short)f2bf(xv[j] - bf2f(h));
            }
        }
        #pragma unroll
        for (int nt = 0; nt < 8; nt++){
            const int fi = (((kc << 3) + nt) << 6 | lane) << 3;
            short8 bh = *(const short8*)&sB[0][fi];
            short8 bl = *(const short8*)&sB[1][fi];
            #pragma unroll
            for (int rt = 0; rt < 2; rt++){
                acc[rt][nt] = __builtin_amdgcn_mfma_f32_16x16x32_bf16(ahi[rt], bh, acc[rt][nt], 0, 0, 0);
                acc[rt][nt] = __builtin_amdgcn_mfma_f32_16x16x32_bf16(alo[rt], bh, acc[rt][nt], 0, 0, 0);
                acc[rt][nt] = __builtin_amdgcn_mfma_f32_16x16x32_bf16(ahi[rt], bl, acc[rt][nt], 0, 0, 0);
            }
        }
    }
    #pragma unroll
    for (int nt = 0; nt < 8; nt++){
        const int col = nt * 16 + ln16;
        const float bv = b[col];
        #pragma unroll
        for (int rt = 0; rt < 2; rt++){
            #pragma unroll
            for (int r = 0; r < 4; r++){
                int row = row0 + rt * 16 + qd * 4 + r;
                if (row < nrows){
                    float y = acc[rt][nt][r] + bv;
                    Y[(size_t)row * DD + col] = lrelu(y);
                }
            }
        }
    }
}

// build A-fragment: 8 bf16 of lrelu(hs_row + hd_row)
__device__ __forceinline__ short8 make_afrag(const unsigned short* ph, const unsigned short* pd){
    uint4 a = *(const uint4*)ph;
    uint4 b = *(const uint4*)pd;
    unsigned au[4] = {a.x, a.y, a.z, a.w};
    unsigned bu[4] = {b.x, b.y, b.z, b.w};
    short8 r;
    #pragma unroll
    for (int i = 0; i < 4; i++){
        float h0 = __uint_as_float(au[i] << 16);
        float h1 = __uint_as_float(au[i] & 0xffff0000u);
        float g0 = __uint_as_float(bu[i] << 16);
        float g1 = __uint_as_float(bu[i] & 0xffff0000u);
        float e0 = lrelu(h0 + g0);
        float e1 = lrelu(h1 + g1);
        r[2 * i]     = (short)f2bf(e0);
        r[2 * i + 1] = (short)f2bf(e1);
    }
    return r;
}

// MFMA edge attention score on SORTED edges; one 128-edge tile per block;
// linear score write.
__global__ __launch_bounds__(256) void edge_score_mfma(
        const unsigned short* hs_b, const unsigned short* hd_b,
        const int2* pairs,
        const unsigned short* wa1p, const float* ba1,
        const float* Wa2, const float* ba2,
        float* s_score, int E){
    __shared__ unsigned short sB[16384];  // 32 KB
    const int tid = threadIdx.x;
    {
        const uint4* g = (const uint4*)wa1p;
        uint4* l = (uint4*)sB;
        #pragma unroll
        for (int t = 0; t < 8; t++) l[tid + 256 * t] = g[tid + 256 * t];
    }
    const int wave = tid >> 6, lane = tid & 63;
    const int qd = lane >> 4, ln16 = lane & 15;
    const int e0 = blockIdx.x * 128 + wave * 32;
    int eid0 = e0 + ln16;       if (eid0 >= E) eid0 = E - 1;
    int eid1 = e0 + 16 + ln16;  if (eid1 >= E) eid1 = E - 1;
    const int2 p0 = pairs[eid0];
    const int2 p1 = pairs[eid1];
    f32x4 acc[2][8];
    #pragma unroll
    for (int rt = 0; rt < 2; rt++)
        #pragma unroll
        for (int nt = 0; nt < 8; nt++)
            acc[rt][nt] = (f32x4){0.f, 0.f, 0.f, 0.f};
    __syncthreads();
    #pragma unroll
    for (int kc = 0; kc < 4; kc++){
        const int koff = kc * 32 + qd * 8;
        short8 af0 = make_afrag(hs_b + (size_t)p0.x * DD + koff, hd_b + (size_t)p0.y * DD + koff);
        short8 af1 = make_afrag(hs_b + (size_t)p1.x * DD + koff, hd_b + (size_t)p1.y * DD + koff);
        #pragma unroll
        for (int nt = 0; nt < 8; nt++){
            short8 bf = *(const short8*)&sB[(((kc << 3) + nt) << 6 | lane) << 3];
            acc[0][nt] = __builtin_amdgcn_mfma_f32_16x16x32_bf16(af0, bf, acc[0][nt], 0, 0, 0);
            acc[1][nt] = __builtin_amdgcn_mfma_f32_16x16x32_bf16(af1, bf, acc[1][nt], 0, 0, 0);
        }
    }
    float b1v[8], w2v[8];
    #pragma unroll
    for (int nt = 0; nt < 8; nt++){
        b1v[nt] = ba1[nt * 16 + ln16];
        w2v[nt] = Wa2[nt * 16 + ln16];
    }
    const float b2 = ba2[0];
    #pragma unroll
    for (int rt = 0; rt < 2; rt++){
        float p[4] = {0.f, 0.f, 0.f, 0.f};
        #pragma unroll
        for (int nt = 0; nt < 8; nt++)
            #pragma unroll
            for (int r = 0; r < 4; r++){
                float z = acc[rt][nt][r] + b1v[nt];
                z = z > 0.f ? z : NEG * z;
                p[r] += z * w2v[nt];
            }
        #pragma unroll
        for (int r = 0; r < 4; r++){
            float v = p[r];
            #pragma unroll
            for (int off = 1; off < 16; off <<= 1) v += __shfl_xor(v, off, 64);
            p[r] = v;
        }
        if (ln16 == 0){
            int row = e0 + rt * 16 + qd * 4;
            #pragma unroll
            for (int r = 0; r < 4; r++)
                if (row + r < E) s_score[row + r] = p[r] + b2;
        }
    }
}

// one wave per dst node: softmax over its CSR segment + weighted bf16 gather.
// nf[n] = sum_e alpha_e * hs[src_e] + (sum_e alpha_e) * hd[n]
__global__ __launch_bounds__(256) void agg_softmax(const unsigned short* hs_b,
        const float* hd, const int* row_off, const int* s_srcs,
        const float* s_score, float* nf, int n_dst){
    const int w = (blockIdx.x * blockDim.x + threadIdx.x) >> 6;
    const int lane = threadIdx.x & 63;
    if (w >= n_dst) return;
    const int beg = row_off[w], end = row_off[w + 1];
    float m = -INFINITY;
    for (int e = beg + lane; e < end; e += 64) m = fmaxf(m, s_score[e]);
    #pragma unroll
    for (int off = 1; off < 64; off <<= 1) m = fmaxf(m, __shfl_xor(m, off, 64));
    float sm = 0.f;
    for (int e = beg + lane; e < end; e += 64) sm += expf(s_score[e] - m);
    #pragma unroll
    for (int off = 1; off < 64; off <<= 1) sm += __shfl_xor(sm, off, 64);
    const float inv = (end > beg) ? 1.f / sm : 0.f;
    float2 acc = make_float2(0.f, 0.f);
    float sa = 0.f;
    int e = beg;
    for (; e + 1 < end; e += 2){
        float a0 = expf(s_score[e] - m) * inv;
        float a1 = expf(s_score[e + 1] - m) * inv;
        int s0 = s_srcs[e], s1 = s_srcs[e + 1];
        ushort2 u0 = *(const ushort2*)(hs_b + (size_t)s0 * DD + lane * 2);
        ushort2 u1 = *(const ushort2*)(hs_b + (size_t)s1 * DD + lane * 2);
        acc.x += a0 * bf2f(u0.x) + a1 * bf2f(u1.x);
        acc.y += a0 * bf2f(u0.y) + a1 * bf2f(u1.y);
        sa += a0 + a1;
    }
    if (e < end){
        float a0 = expf(s_score[e] - m) * inv;
        int s0 = s_srcs[e];
        ushort2 u0 = *(const ushort2*)(hs_b + (size_t)s0 * DD + lane * 2);
        acc.x += a0 * bf2f(u0.x);
        acc.y += a0 * bf2f(u0.y);
        sa += a0;
    }
    float2 h = *(const float2*)(hd + (size_t)w * DD + lane * 2);
    float2 out;
    out.x = acc.x + sa * h.x;
    out.y = acc.y + sa * h.y;
    *(float2*)(nf + (size_t)w * DD + lane * 2) = out;
}

extern "C" void kernel_launch(void* const* d_in, const int* in_sizes, int n_in,
                              void* d_out, int out_size, void* d_ws, size_t ws_size,
                              hipStream_t stream){
    const float* feat_src = (const float*)d_in[0];
    const float* feat_dst = (const float*)d_in[1];
    const int*   src_idx  = (const int*)d_in[2];
    const int*   dst_idx  = (const int*)d_in[3];
    const float* W_src = (const float*)d_in[4];
    const float* b_src = (const float*)d_in[5];
    const float* W_dst = (const float*)d_in[6];
    const float* b_dst = (const float*)d_in[7];
    const float* W_a1  = (const float*)d_in[8];
    const float* b_a1  = (const float*)d_in[9];
    const float* W_a2  = (const float*)d_in[10];
    const float* b_a2  = (const float*)d_in[11];
    const float* W_out = (const float*)d_in[12];
    const float* b_out = (const float*)d_in[13];
    const int n_src = in_sizes[0] / DD;
    const int n_dst = in_sizes[1] / DD;
    const int E = in_sizes[2];
    const int nchunks = (n_dst + SCHUNK - 1) / SCHUNK;

    // workspace layout (all 16B-aligned segments)
    char* p = (char*)d_ws;
    float* hd = (float*)p;                      p += (size_t)n_dst * DD * 4;
    unsigned short* hs_b = (unsigned short*)p;  p += (size_t)n_src * DD * 2;
    unsigned short* hd_b = (unsigned short*)p;  p += (size_t)n_dst * DD * 2;
    unsigned short* wpack = (unsigned short*)p; p += 7 * 16384 * 2;
    float* s_score = (float*)p;                 p += (size_t)E * 4;
    int2* pairs = (int2*)p;                     p += (size_t)E * 8;
    int* s_srcs = (int*)p;                      p += (size_t)E * 4;
    int* deg = (int*)p;                         p += (size_t)n_dst * 4;
    int* cursor = (int*)p;                      p += (size_t)n_dst * 4;
    int* part = (int*)p;                        p += 64 * 4;
    int* row_off = (int*)p;                     p += ((size_t)n_dst + 1) * 4;
    float* nf = (float*)d_out;

    const unsigned short* wa1p    = wpack;
    const unsigned short* wsrc_hi = wpack + 1 * 16384;
    const unsigned short* wsrc_lo = wpack + 2 * 16384;
    const unsigned short* wdst_hi = wpack + 3 * 16384;
    const unsigned short* wdst_lo = wpack + 4 * 16384;
    const unsigned short* wout_hi = wpack + 5 * 16384;
    const unsigned short* wout_lo = wpack + 6 * 16384;

    init_deg<<<(n_dst + 255) / 256, 256, 0, stream>>>(deg, n_dst);
    hist_kernel<<<(E + 255) / 256, 256, 0, stream>>>(dst_idx, deg, E);
    scan1<<<nchunks, 1024, 0, stream>>>(deg, part, n_dst);
    scan2<<<nchunks, 1024, 0, stream>>>(deg, part, row_off, cursor, n_dst, nchunks);
    pack_weights<<<(7 * 16384 + 255) / 256, 256, 0, stream>>>(W_a1, W_src, W_dst, W_out, wpack);
    scatter_pairs<<<(E + 255) / 256, 256, 0, stream>>>(src_idx, dst_idx, cursor,
                                                       pairs, s_srcs, E);
    const int g1 = (n_src + 127) / 128;
    const int g2 = (n_dst + 127) / 128;
    lin2_mfma<<<g1 + g2, 256, 0, stream>>>(feat_src, wsrc_hi, wsrc_lo, b_src, hs_b, n_src, g1,
                                           feat_dst, wdst_hi, wdst_lo, b_dst, hd, hd_b, n_dst);
    edge_score_mfma<<<(E + 127) / 128, 256, 0, stream>>>(hs_b, hd_b, pairs, wa1p, b_a1,
                                                         W_a2, b_a2, s_score, E);
    agg_softmax<<<((size_t)n_dst * 64 + 255) / 256, 256, 0, stream>>>(hs_b, hd, row_off,
                                                                      s_srcs, s_score, nf, n_dst);
    lin_mfma<<<g2, 256, 0, stream>>>(nf, wout_hi, wout_lo, b_out, nf, n_dst);
}

// Round 7
// 330.290 us; speedup vs baseline: 1.1950x; 1.0741x over previous
//
#include <hip/hip_runtime.h>
#include <math.h>

#define DD 128
#define NEG 0.01f
#define SCHUNK 4096

typedef __attribute__((ext_vector_type(8))) short short8;
typedef __attribute__((ext_vector_type(4))) float f32x4;

__device__ __forceinline__ float lrelu(float x){ return x > 0.f ? x : NEG * x; }

// fp32 -> bf16 round-to-nearest-even (finite inputs)
__device__ __forceinline__ unsigned short f2bf(float f){
    unsigned u = __float_as_uint(f);
    u += 0x7fffu + ((u >> 16) & 1u);
    return (unsigned short)(u >> 16);
}
__device__ __forceinline__ float bf2f(unsigned short h){
    return __uint_as_float(((unsigned)h) << 16);
}

__global__ void init_deg(int* deg, int n_dst){
    int i = blockIdx.x * blockDim.x + threadIdx.x;
    if (i < n_dst) deg[i] = 0;
}

__global__ void hist_kernel(const int* dst, int* deg, int E){
    int i = blockIdx.x * blockDim.x + threadIdx.x;
    if (i < E) atomicAdd(&deg[dst[i]], 1);
}

// two-level scan, level 1: per-chunk sums (chunk = 4096 ints)
__global__ __launch_bounds__(1024) void scan1(const int* deg, int* part, int n){
    __shared__ int wsum[16];
    const int tid = threadIdx.x;
    const int lane = tid & 63, wid = tid >> 6;
    int i4 = blockIdx.x * SCHUNK + tid * 4;
    int4 v = make_int4(0, 0, 0, 0);
    if (i4 + 3 < n) v = *(const int4*)(deg + i4);
    else {
        if (i4 + 0 < n) v.x = deg[i4 + 0];
        if (i4 + 1 < n) v.y = deg[i4 + 1];
        if (i4 + 2 < n) v.z = deg[i4 + 2];
        if (i4 + 3 < n) v.w = deg[i4 + 3];
    }
    int t = v.x + v.y + v.z + v.w;
    #pragma unroll
    for (int off = 1; off < 64; off <<= 1) t += __shfl_xor(t, off, 64);
    if (lane == 0) wsum[wid] = t;
    __syncthreads();
    if (tid == 0){
        int s = 0;
        #pragma unroll
        for (int j = 0; j < 16; j++) s += wsum[j];
        part[blockIdx.x] = s;
    }
}

// two-level scan, level 2: exclusive offsets + cursor copy
__global__ __launch_bounds__(1024) void scan2(const int* deg, const int* part,
        int* row_off, int* cursor, int n, int nchunks){
    __shared__ int wsum[16];
    const int tid = threadIdx.x;
    const int lane = tid & 63, wid = tid >> 6;
    const int b = blockIdx.x;
    int carry = 0;
    for (int j = 0; j < b; j++) carry += part[j];
    int i4 = b * SCHUNK + tid * 4;
    int4 v = make_int4(0, 0, 0, 0);
    if (i4 + 3 < n) v = *(const int4*)(deg + i4);
    else {
        if (i4 + 0 < n) v.x = deg[i4 + 0];
        if (i4 + 1 < n) v.y = deg[i4 + 1];
        if (i4 + 2 < n) v.z = deg[i4 + 2];
        if (i4 + 3 < n) v.w = deg[i4 + 3];
    }
    int tsum = v.x + v.y + v.z + v.w;
    int x = tsum;
    #pragma unroll
    for (int off = 1; off < 64; off <<= 1){
        int t = __shfl_up(x, off, 64);
        if (lane >= off) x += t;
    }
    if (lane == 63) wsum[wid] = x;
    __syncthreads();
    int wprefix = 0;
    #pragma unroll
    for (int j = 0; j < 16; j++) if (j < wid) wprefix += wsum[j];
    int excl = carry + wprefix + (x - tsum);
    if (i4 + 3 < n){
        int4 o;
        o.x = excl; o.y = excl + v.x; o.z = o.y + v.y; o.w = o.z + v.z;
        *(int4*)(row_off + i4) = o;
        *(int4*)(cursor + i4) = o;
    } else {
        int a = excl;
        if (i4 + 0 < n){ row_off[i4 + 0] = a; cursor[i4 + 0] = a; a += v.x; }
        if (i4 + 1 < n){ row_off[i4 + 1] = a; cursor[i4 + 1] = a; a += v.y; }
        if (i4 + 2 < n){ row_off[i4 + 2] = a; cursor[i4 + 2] = a; a += v.z; }
        if (i4 + 3 < n){ row_off[i4 + 3] = a; cursor[i4 + 3] = a; }
    }
    if (b == 0 && tid == 0){
        int tot = 0;
        for (int j = 0; j < nchunks; j++) tot += part[j];
        row_off[n] = tot;
    }
}

// bucket edges by dst: sorted (src,dst) pairs in CSR order + SoA src copy
__global__ void scatter_pairs(const int* src, const int* dst, int* cursor,
                              int2* pairs, int* s_srcs, int E){
    int i = blockIdx.x * blockDim.x + threadIdx.x;
    if (i < E){
        int d = dst[i];
        int s = src[i];
        int pos = atomicAdd(&cursor[d], 1);
        pairs[pos] = make_int2(s, d);
        s_srcs[pos] = s;
    }
}

// pack 4 weight matrices into bf16 MFMA B-fragment-linear order.
// seg 0: Wa1 hi; 1,2: Wsrc hi,lo; 3,4: Wdst hi,lo; 5,6: Wout hi,lo
__global__ void pack_weights(const float* Wa1, const float* Wsrc,
                             const float* Wdst, const float* Wout,
                             unsigned short* out){
    int i = blockIdx.x * blockDim.x + threadIdx.x;   // 7*16384
    if (i >= 7 * 16384) return;
    int seg = i >> 14, t = i & 16383;
    int j = t & 7, lane = (t >> 3) & 63, nt = (t >> 9) & 7, kc = t >> 12;
    int k = kc * 32 + (lane >> 4) * 8 + j;
    int n = nt * 16 + (lane & 15);
    const float* W = (seg == 0) ? Wa1 : (seg <= 2) ? Wsrc : (seg <= 4) ? Wdst : Wout;
    float w = W[k * DD + n];
    unsigned short hi = f2bf(w);
    unsigned short val = hi;
    if (seg == 2 || seg == 4 || seg == 6) val = f2bf(w - bf2f(hi));
    out[i] = val;
}

// Node linear via MFMA, bf16 hi/lo split (~fp32 accuracy).
// Y[r] = act(X[r] @ W + b). 128 rows/block (4 waves x 32 rows).
// Fused variant: blocks [0,g1) process (X1,W1,b1)->Yb1; blocks [g1,..) process
// (X2,W2,b2)->(Y2 opt),Yb2.
__global__ __launch_bounds__(256) void lin2_mfma(
        const float* X1, const unsigned short* W1hi, const unsigned short* W1lo,
        const float* b1, unsigned short* Yb1, int n1, int g1,
        const float* X2, const unsigned short* W2hi, const unsigned short* W2lo,
        const float* b2, float* Y2, unsigned short* Yb2, int n2){
    __shared__ unsigned short sB[2][16384];   // 64 KB
    const int tid = threadIdx.x;
    const int second = (blockIdx.x >= g1);
    const float* X = second ? X2 : X1;
    const unsigned short* Whi = second ? W2hi : W1hi;
    const unsigned short* Wlo = second ? W2lo : W1lo;
    const float* b = second ? b2 : b1;
    float* Y = second ? Y2 : (float*)nullptr;
    unsigned short* Yb = second ? Yb2 : Yb1;
    const int nrows = second ? n2 : n1;
    const int bidx = second ? (blockIdx.x - g1) : blockIdx.x;
    {
        const uint4* gh = (const uint4*)Whi;
        const uint4* gl = (const uint4*)Wlo;
        uint4* lh = (uint4*)sB[0];
        uint4* ll = (uint4*)sB[1];
        #pragma unroll
        for (int t = 0; t < 8; t++){
            lh[tid + 256 * t] = gh[tid + 256 * t];
            ll[tid + 256 * t] = gl[tid + 256 * t];
        }
    }
    const int wave = tid >> 6, lane = tid & 63;
    const int qd = lane >> 4, ln16 = lane & 15;
    const int row0 = bidx * 128 + wave * 32;
    int r0 = row0 + ln16;       if (r0 >= nrows) r0 = nrows - 1;
    int r1 = row0 + 16 + ln16;  if (r1 >= nrows) r1 = nrows - 1;
    f32x4 acc[2][8];
    #pragma unroll
    for (int rt = 0; rt < 2; rt++)
        #pragma unroll
        for (int nt = 0; nt < 8; nt++)
            acc[rt][nt] = (f32x4){0.f, 0.f, 0.f, 0.f};
    __syncthreads();
    #pragma unroll
    for (int kc = 0; kc < 4; kc++){
        const int koff = kc * 32 + qd * 8;
        short8 ahi[2], alo[2];
        const float* px[2] = {X + (size_t)r0 * DD + koff, X + (size_t)r1 * DD + koff};
        #pragma unroll
        for (int rt = 0; rt < 2; rt++){
            float4 v0 = *(const float4*)(px[rt]);
            float4 v1 = *(const float4*)(px[rt] + 4);
            float xv[8] = {v0.x, v0.y, v0.z, v0.w, v1.x, v1.y, v1.z, v1.w};
            #pragma unroll
            for (int j = 0; j < 8; j++){
                unsigned short h = f2bf(xv[j]);
                ahi[rt][j] = (short)h;
                alo[rt][j] = (short)f2bf(xv[j] - bf2f(h));
            }
        }
        #pragma unroll
        for (int nt = 0; nt < 8; nt++){
            const int fi = (((kc << 3) + nt) << 6 | lane) << 3;
            short8 bh = *(const short8*)&sB[0][fi];
            short8 bl = *(const short8*)&sB[1][fi];
            #pragma unroll
            for (int rt = 0; rt < 2; rt++){
                acc[rt][nt] = __builtin_amdgcn_mfma_f32_16x16x32_bf16(ahi[rt], bh, acc[rt][nt], 0, 0, 0);
                acc[rt][nt] = __builtin_amdgcn_mfma_f32_16x16x32_bf16(alo[rt], bh, acc[rt][nt], 0, 0, 0);
                acc[rt][nt] = __builtin_amdgcn_mfma_f32_16x16x32_bf16(ahi[rt], bl, acc[rt][nt], 0, 0, 0);
            }
        }
    }
    #pragma unroll
    for (int nt = 0; nt < 8; nt++){
        const int col = nt * 16 + ln16;
        const float bv = b[col];
        #pragma unroll
        for (int rt = 0; rt < 2; rt++){
            #pragma unroll
            for (int r = 0; r < 4; r++){
                int row = row0 + rt * 16 + qd * 4 + r;
                if (row < nrows){
                    float y = acc[rt][nt][r] + bv;
                    if (Y) Y[(size_t)row * DD + col] = y;
                    if (Yb) Yb[(size_t)row * DD + col] = f2bf(y);
                }
            }
        }
    }
}

// Final linear (in-place capable): Y = lrelu(X @ W + b)
__global__ __launch_bounds__(256) void lin_mfma(const float* X,
        const unsigned short* Whi, const unsigned short* Wlo, const float* b,
        float* Y, int nrows){
    __shared__ unsigned short sB[2][16384];
    const int tid = threadIdx.x;
    {
        const uint4* gh = (const uint4*)Whi;
        const uint4* gl = (const uint4*)Wlo;
        uint4* lh = (uint4*)sB[0];
        uint4* ll = (uint4*)sB[1];
        #pragma unroll
        for (int t = 0; t < 8; t++){
            lh[tid + 256 * t] = gh[tid + 256 * t];
            ll[tid + 256 * t] = gl[tid + 256 * t];
        }
    }
    const int wave = tid >> 6, lane = tid & 63;
    const int qd = lane >> 4, ln16 = lane & 15;
    const int row0 = blockIdx.x * 128 + wave * 32;
    int r0 = row0 + ln16;       if (r0 >= nrows) r0 = nrows - 1;
    int r1 = row0 + 16 + ln16;  if (r1 >= nrows) r1 = nrows - 1;
    f32x4 acc[2][8];
    #pragma unroll
    for (int rt = 0; rt < 2; rt++)
        #pragma unroll
        for (int nt = 0; nt < 8; nt++)
            acc[rt][nt] = (f32x4){0.f, 0.f, 0.f, 0.f};
    __syncthreads();
    #pragma unroll
    for (int kc = 0; kc < 4; kc++){
        const int koff = kc * 32 + qd * 8;
        short8 ahi[2], alo[2];
        const float* px[2] = {X + (size_t)r0 * DD + koff, X + (size_t)r1 * DD + koff};
        #pragma unroll
        for (int rt = 0; rt < 2; rt++){
            float4 v0 = *(const float4*)(px[rt]);
            float4 v1 = *(const float4*)(px[rt] + 4);
            float xv[8] = {v0.x, v0.y, v0.z, v0.w, v1.x, v1.y, v1.z, v1.w};
            #pragma unroll
            for (int j = 0; j < 8; j++){
                unsigned short h = f2bf(xv[j]);
                ahi[rt][j] = (short)h;
                alo[rt][j] = (short)f2bf(xv[j] - bf2f(h));
            }
        }
        #pragma unroll
        for (int nt = 0; nt < 8; nt++){
            const int fi = (((kc << 3) + nt) << 6 | lane) << 3;
            short8 bh = *(const short8*)&sB[0][fi];
            short8 bl = *(const short8*)&sB[1][fi];
            #pragma unroll
            for (int rt = 0; rt < 2; rt++){
                acc[rt][nt] = __builtin_amdgcn_mfma_f32_16x16x32_bf16(ahi[rt], bh, acc[rt][nt], 0, 0, 0);
                acc[rt][nt] = __builtin_amdgcn_mfma_f32_16x16x32_bf16(alo[rt], bh, acc[rt][nt], 0, 0, 0);
                acc[rt][nt] = __builtin_amdgcn_mfma_f32_16x16x32_bf16(ahi[rt], bl, acc[rt][nt], 0, 0, 0);
            }
        }
    }
    #pragma unroll
    for (int nt = 0; nt < 8; nt++){
        const int col = nt * 16 + ln16;
        const float bv = b[col];
        #pragma unroll
        for (int rt = 0; rt < 2; rt++){
            #pragma unroll
            for (int r = 0; r < 4; r++){
                int row = row0 + rt * 16 + qd * 4 + r;
                if (row < nrows){
                    float y = acc[rt][nt][r] + bv;
                    Y[(size_t)row * DD + col] = lrelu(y);
                }
            }
        }
    }
}

// build A-fragment: 8 bf16 of lrelu(hs_row + hd_row); truncation pack
// (round-to-zero: sign-symmetric, ~0.2% avg |err| vs 0.4% bf16 quantum)
__device__ __forceinline__ short8 make_afrag(const unsigned short* ph, const unsigned short* pd){
    uint4 a = *(const uint4*)ph;
    uint4 b = *(const uint4*)pd;
    unsigned au[4] = {a.x, a.y, a.z, a.w};
    unsigned bu[4] = {b.x, b.y, b.z, b.w};
    int4 out;
    int* op = (int*)&out;
    #pragma unroll
    for (int i = 0; i < 4; i++){
        float h0 = __uint_as_float(au[i] << 16);
        float h1 = __uint_as_float(au[i] & 0xffff0000u);
        float g0 = __uint_as_float(bu[i] << 16);
        float g1 = __uint_as_float(bu[i] & 0xffff0000u);
        float e0 = lrelu(h0 + g0);
        float e1 = lrelu(h1 + g1);
        op[i] = (int)((__float_as_uint(e0) >> 16) | (__float_as_uint(e1) & 0xffff0000u));
    }
    return *(short8*)&out;
}

// MFMA edge attention score on SORTED edges; one 128-edge tile per block.
// rt-serialized: only 8 f32x4 accumulators (32 AGPR) live at a time.
// Writes w = exp(score) directly (softmax max-shift cancels in alpha).
__global__ __launch_bounds__(256) void edge_score_mfma(
        const unsigned short* hs_b, const unsigned short* hd_b,
        const int2* pairs,
        const unsigned short* wa1p, const float* ba1,
        const float* Wa2, const float* ba2,
        float* s_w, int E){
    __shared__ unsigned short sB[16384];  // 32 KB
    const int tid = threadIdx.x;
    {
        const uint4* g = (const uint4*)wa1p;
        uint4* l = (uint4*)sB;
        #pragma unroll
        for (int t = 0; t < 8; t++) l[tid + 256 * t] = g[tid + 256 * t];
    }
    const int wave = tid >> 6, lane = tid & 63;
    const int qd = lane >> 4, ln16 = lane & 15;
    const int e0 = blockIdx.x * 128 + wave * 32;
    float b1v[8], w2v[8];
    #pragma unroll
    for (int nt = 0; nt < 8; nt++){
        b1v[nt] = ba1[nt * 16 + ln16];
        w2v[nt] = Wa2[nt * 16 + ln16];
    }
    const float b2 = ba2[0];
    __syncthreads();
    for (int rt = 0; rt < 2; rt++){
        int eid = e0 + rt * 16 + ln16;
        if (eid >= E) eid = E - 1;
        const int2 pp = pairs[eid];
        f32x4 acc[8];
        #pragma unroll
        for (int nt = 0; nt < 8; nt++) acc[nt] = (f32x4){0.f, 0.f, 0.f, 0.f};
        #pragma unroll
        for (int kc = 0; kc < 4; kc++){
            const int koff = kc * 32 + qd * 8;
            short8 af = make_afrag(hs_b + (size_t)pp.x * DD + koff,
                                   hd_b + (size_t)pp.y * DD + koff);
            #pragma unroll
            for (int nt = 0; nt < 8; nt++){
                short8 bf = *(const short8*)&sB[(((kc << 3) + nt) << 6 | lane) << 3];
                acc[nt] = __builtin_amdgcn_mfma_f32_16x16x32_bf16(af, bf, acc[nt], 0, 0, 0);
            }
        }
        float p[4] = {0.f, 0.f, 0.f, 0.f};
        #pragma unroll
        for (int nt = 0; nt < 8; nt++)
            #pragma unroll
            for (int r = 0; r < 4; r++){
                float z = acc[nt][r] + b1v[nt];
                z = z > 0.f ? z : NEG * z;
                p[r] += z * w2v[nt];
            }
        #pragma unroll
        for (int r = 0; r < 4; r++){
            float v = p[r];
            #pragma unroll
            for (int off = 1; off < 16; off <<= 1) v += __shfl_xor(v, off, 64);
            p[r] = expf(v + b2);
        }
        if (ln16 == 0){
            int row = e0 + rt * 16 + qd * 4;
            #pragma unroll
            for (int r = 0; r < 4; r++)
                if (row + r < E) s_w[row + r] = p[r];
        }
    }
}

// one wave per dst node, single pass:
// nf[n] = (sum_e w_e * hs[src_e]) / (sum_e w_e) + hd[n]   (hd in bf16)
__global__ __launch_bounds__(256) void agg_softmax(const unsigned short* hs_b,
        const unsigned short* hd_b, const int* row_off, const int* s_srcs,
        const float* s_w, float* nf, int n_dst){
    const int w = (blockIdx.x * blockDim.x + threadIdx.x) >> 6;
    const int lane = threadIdx.x & 63;
    if (w >= n_dst) return;
    const int beg = row_off[w], end = row_off[w + 1];
    float2 acc = make_float2(0.f, 0.f);
    float sa = 0.f;
    int e = beg;
    for (; e + 3 < end; e += 4){
        float w0 = s_w[e], w1 = s_w[e + 1], w2 = s_w[e + 2], w3 = s_w[e + 3];
        int s0 = s_srcs[e], s1 = s_srcs[e + 1], s2 = s_srcs[e + 2], s3 = s_srcs[e + 3];
        ushort2 u0 = *(const ushort2*)(hs_b + (size_t)s0 * DD + lane * 2);
        ushort2 u1 = *(const ushort2*)(hs_b + (size_t)s1 * DD + lane * 2);
        ushort2 u2 = *(const ushort2*)(hs_b + (size_t)s2 * DD + lane * 2);
        ushort2 u3 = *(const ushort2*)(hs_b + (size_t)s3 * DD + lane * 2);
        acc.x += w0 * bf2f(u0.x) + w1 * bf2f(u1.x) + w2 * bf2f(u2.x) + w3 * bf2f(u3.x);
        acc.y += w0 * bf2f(u0.y) + w1 * bf2f(u1.y) + w2 * bf2f(u2.y) + w3 * bf2f(u3.y);
        sa += (w0 + w1) + (w2 + w3);
    }
    for (; e < end; e++){
        float w0 = s_w[e];
        int s0 = s_srcs[e];
        ushort2 u0 = *(const ushort2*)(hs_b + (size_t)s0 * DD + lane * 2);
        acc.x += w0 * bf2f(u0.x);
        acc.y += w0 * bf2f(u0.y);
        sa += w0;
    }
    const float inv = (end > beg) ? 1.f / sa : 0.f;
    ushort2 hu = *(const ushort2*)(hd_b + (size_t)w * DD + lane * 2);
    const float hx = (end > beg) ? bf2f(hu.x) : 0.f;
    const float hy = (end > beg) ? bf2f(hu.y) : 0.f;
    float2 out;
    out.x = acc.x * inv + hx;
    out.y = acc.y * inv + hy;
    *(float2*)(nf + (size_t)w * DD + lane * 2) = out;
}

extern "C" void kernel_launch(void* const* d_in, const int* in_sizes, int n_in,
                              void* d_out, int out_size, void* d_ws, size_t ws_size,
                              hipStream_t stream){
    const float* feat_src = (const float*)d_in[0];
    const float* feat_dst = (const float*)d_in[1];
    const int*   src_idx  = (const int*)d_in[2];
    const int*   dst_idx  = (const int*)d_in[3];
    const float* W_src = (const float*)d_in[4];
    const float* b_src = (const float*)d_in[5];
    const float* W_dst = (const float*)d_in[6];
    const float* b_dst = (const float*)d_in[7];
    const float* W_a1  = (const float*)d_in[8];
    const float* b_a1  = (const float*)d_in[9];
    const float* W_a2  = (const float*)d_in[10];
    const float* b_a2  = (const float*)d_in[11];
    const float* W_out = (const float*)d_in[12];
    const float* b_out = (const float*)d_in[13];
    const int n_src = in_sizes[0] / DD;
    const int n_dst = in_sizes[1] / DD;
    const int E = in_sizes[2];
    const int nchunks = (n_dst + SCHUNK - 1) / SCHUNK;

    // workspace layout (all 16B-aligned segments)
    char* p = (char*)d_ws;
    unsigned short* hs_b = (unsigned short*)p;  p += (size_t)n_src * DD * 2;
    unsigned short* hd_b = (unsigned short*)p;  p += (size_t)n_dst * DD * 2;
    unsigned short* wpack = (unsigned short*)p; p += 7 * 16384 * 2;
    float* s_w = (float*)p;                     p += (size_t)E * 4;
    int2* pairs = (int2*)p;                     p += (size_t)E * 8;
    int* s_srcs = (int*)p;                      p += (size_t)E * 4;
    int* deg = (int*)p;                         p += (size_t)n_dst * 4;
    int* cursor = (int*)p;                      p += (size_t)n_dst * 4;
    int* part = (int*)p;                        p += 64 * 4;
    int* row_off = (int*)p;                     p += ((size_t)n_dst + 1) * 4;
    float* nf = (float*)d_out;

    const unsigned short* wa1p    = wpack;
    const unsigned short* wsrc_hi = wpack + 1 * 16384;
    const unsigned short* wsrc_lo = wpack + 2 * 16384;
    const unsigned short* wdst_hi = wpack + 3 * 16384;
    const unsigned short* wdst_lo = wpack + 4 * 16384;
    const unsigned short* wout_hi = wpack + 5 * 16384;
    const unsigned short* wout_lo = wpack + 6 * 16384;

    init_deg<<<(n_dst + 255) / 256, 256, 0, stream>>>(deg, n_dst);
    hist_kernel<<<(E + 255) / 256, 256, 0, stream>>>(dst_idx, deg, E);
    scan1<<<nchunks, 1024, 0, stream>>>(deg, part, n_dst);
    scan2<<<nchunks, 1024, 0, stream>>>(deg, part, row_off, cursor, n_dst, nchunks);
    pack_weights<<<(7 * 16384 + 255) / 256, 256, 0, stream>>>(W_a1, W_src, W_dst, W_out, wpack);
    scatter_pairs<<<(E + 255) / 256, 256, 0, stream>>>(src_idx, dst_idx, cursor,
                                                       pairs, s_srcs, E);
    const int g1 = (n_src + 127) / 128;
    const int g2 = (n_dst + 127) / 128;
    lin2_mfma<<<g1 + g2, 256, 0, stream>>>(feat_src, wsrc_hi, wsrc_lo, b_src, hs_b, n_src, g1,
                                           feat_dst, wdst_hi, wdst_lo, b_dst,
                                           (float*)nullptr, hd_b, n_dst);
    edge_score_mfma<<<(E + 127) / 128, 256, 0, stream>>>(hs_b, hd_b, pairs, wa1p, b_a1,
                                                         W_a2, b_a2, s_w, E);
    agg_softmax<<<((size_t)n_dst * 64 + 255) / 256, 256, 0, stream>>>(hs_b, hd_b, row_off,
                                                                      s_srcs, s_w, nf, n_dst);
    lin_mfma<<<g2, 256, 0, stream>>>(nf, wout_hi, wout_lo, b_out, nf, n_dst);
}

// Round 8
// 325.028 us; speedup vs baseline: 1.2144x; 1.0162x over previous
//
#include <hip/hip_runtime.h>
#include <math.h>

#define DD 128
#define NEG 0.01f
#define SCHUNK 4096

typedef __attribute__((ext_vector_type(8))) _Float16 half8;
typedef __attribute__((ext_vector_type(4))) float f32x4;

__device__ __forceinline__ float lrelu(float x){ return x > 0.f ? x : NEG * x; }

__device__ __forceinline__ unsigned short h2u(_Float16 h){
    union { _Float16 h; unsigned short u; } v; v.h = h; return v.u;
}
__device__ __forceinline__ _Float16 u2h(unsigned short u){
    union { unsigned short u; _Float16 h; } v; v.u = u; return v.h;
}

__global__ void hist_pack(const int* dst, int* deg, int E, int nhist,
                          const float* Wa1, const float* Wsrc,
                          const float* Wdst, const float* Wout,
                          unsigned short* wpack){
    const int bid = blockIdx.x;
    if (bid < nhist){
        int i = bid * 256 + threadIdx.x;
        if (i < E) atomicAdd(&deg[dst[i]], 1);
    } else {
        int i = (bid - nhist) * 256 + threadIdx.x;   // [0, 7*16384)
        if (i >= 7 * 16384) return;
        int seg = i >> 14, t = i & 16383;
        int j = t & 7, lane = (t >> 3) & 63, nt = (t >> 9) & 7, kc = t >> 12;
        int k = kc * 32 + (lane >> 4) * 8 + j;
        int n = nt * 16 + (lane & 15);
        const float* W = (seg == 0) ? Wa1 : (seg <= 2) ? Wsrc : (seg <= 4) ? Wdst : Wout;
        float w = W[k * DD + n];
        _Float16 hi = (_Float16)w;
        unsigned short val = h2u(hi);
        if (seg == 2 || seg == 4 || seg == 6) val = h2u((_Float16)(w - (float)hi));
        wpack[i] = val;
    }
}

// two-level scan, level 1: per-chunk sums (chunk = 4096 ints)
__global__ __launch_bounds__(1024) void scan1(const int* deg, int* part, int n){
    __shared__ int wsum[16];
    const int tid = threadIdx.x;
    const int lane = tid & 63, wid = tid >> 6;
    int i4 = blockIdx.x * SCHUNK + tid * 4;
    int4 v = make_int4(0, 0, 0, 0);
    if (i4 + 3 < n) v = *(const int4*)(deg + i4);
    else {
        if (i4 + 0 < n) v.x = deg[i4 + 0];
        if (i4 + 1 < n) v.y = deg[i4 + 1];
        if (i4 + 2 < n) v.z = deg[i4 + 2];
        if (i4 + 3 < n) v.w = deg[i4 + 3];
    }
    int t = v.x + v.y + v.z + v.w;
    #pragma unroll
    for (int off = 1; off < 64; off <<= 1) t += __shfl_xor(t, off, 64);
    if (lane == 0) wsum[wid] = t;
    __syncthreads();
    if (tid == 0){
        int s = 0;
        #pragma unroll
        for (int j = 0; j < 16; j++) s += wsum[j];
        part[blockIdx.x] = s;
    }
}

// two-level scan, level 2: exclusive offsets + cursor copy
__global__ __launch_bounds__(1024) void scan2(const int* deg, const int* part,
        int* row_off, int* cursor, int n, int nchunks){
    __shared__ int wsum[16];
    const int tid = threadIdx.x;
    const int lane = tid & 63, wid = tid >> 6;
    const int b = blockIdx.x;
    int carry = 0;
    for (int j = 0; j < b; j++) carry += part[j];
    int i4 = b * SCHUNK + tid * 4;
    int4 v = make_int4(0, 0, 0, 0);
    if (i4 + 3 < n) v = *(const int4*)(deg + i4);
    else {
        if (i4 + 0 < n) v.x = deg[i4 + 0];
        if (i4 + 1 < n) v.y = deg[i4 + 1];
        if (i4 + 2 < n) v.z = deg[i4 + 2];
        if (i4 + 3 < n) v.w = deg[i4 + 3];
    }
    int tsum = v.x + v.y + v.z + v.w;
    int x = tsum;
    #pragma unroll
    for (int off = 1; off < 64; off <<= 1){
        int t = __shfl_up(x, off, 64);
        if (lane >= off) x += t;
    }
    if (lane == 63) wsum[wid] = x;
    __syncthreads();
    int wprefix = 0;
    #pragma unroll
    for (int j = 0; j < 16; j++) if (j < wid) wprefix += wsum[j];
    int excl = carry + wprefix + (x - tsum);
    if (i4 + 3 < n){
        int4 o;
        o.x = excl; o.y = excl + v.x; o.z = o.y + v.y; o.w = o.z + v.z;
        *(int4*)(row_off + i4) = o;
        *(int4*)(cursor + i4) = o;
    } else {
        int a = excl;
        if (i4 + 0 < n){ row_off[i4 + 0] = a; cursor[i4 + 0] = a; a += v.x; }
        if (i4 + 1 < n){ row_off[i4 + 1] = a; cursor[i4 + 1] = a; a += v.y; }
        if (i4 + 2 < n){ row_off[i4 + 2] = a; cursor[i4 + 2] = a; a += v.z; }
        if (i4 + 3 < n){ row_off[i4 + 3] = a; cursor[i4 + 3] = a; }
    }
    if (b == 0 && tid == 0){
        int tot = 0;
        for (int j = 0; j < nchunks; j++) tot += part[j];
        row_off[n] = tot;
    }
}

// bucket edges by dst: sorted (src,dst) pairs in CSR order + SoA src copy
__global__ void scatter_pairs(const int* src, const int* dst, int* cursor,
                              int2* pairs, int* s_srcs, int E){
    int i = blockIdx.x * blockDim.x + threadIdx.x;
    if (i < E){
        int d = dst[i];
        int s = src[i];
        int pos = atomicAdd(&cursor[d], 1);
        pairs[pos] = make_int2(s, d);
        s_srcs[pos] = s;
    }
}

// Node linear via MFMA, fp16 hi/lo split (~fp32 accuracy).
// Y[r] = X[r] @ W + b. 128 rows/block (4 waves x 32 rows).
// Fused: blocks [0,g1): (X1,W1,b1)->Yb1; blocks [g1,..): (X2,W2,b2)->Yb2.
__global__ __launch_bounds__(256) void lin2_mfma(
        const float* X1, const unsigned short* W1hi, const unsigned short* W1lo,
        const float* b1, unsigned short* Yb1, int n1, int g1,
        const float* X2, const unsigned short* W2hi, const unsigned short* W2lo,
        const float* b2, unsigned short* Yb2, int n2){
    __shared__ unsigned short sB[2][16384];   // 64 KB
    const int tid = threadIdx.x;
    const int second = (blockIdx.x >= g1);
    const float* X = second ? X2 : X1;
    const unsigned short* Whi = second ? W2hi : W1hi;
    const unsigned short* Wlo = second ? W2lo : W1lo;
    const float* b = second ? b2 : b1;
    unsigned short* Yb = second ? Yb2 : Yb1;
    const int nrows = second ? n2 : n1;
    const int bidx = second ? (blockIdx.x - g1) : blockIdx.x;
    {
        const uint4* gh = (const uint4*)Whi;
        const uint4* gl = (const uint4*)Wlo;
        uint4* lh = (uint4*)sB[0];
        uint4* ll = (uint4*)sB[1];
        #pragma unroll
        for (int t = 0; t < 8; t++){
            lh[tid + 256 * t] = gh[tid + 256 * t];
            ll[tid + 256 * t] = gl[tid + 256 * t];
        }
    }
    const int wave = tid >> 6, lane = tid & 63;
    const int qd = lane >> 4, ln16 = lane & 15;
    const int row0 = bidx * 128 + wave * 32;
    int r0 = row0 + ln16;       if (r0 >= nrows) r0 = nrows - 1;
    int r1 = row0 + 16 + ln16;  if (r1 >= nrows) r1 = nrows - 1;
    f32x4 acc[2][8];
    #pragma unroll
    for (int rt = 0; rt < 2; rt++)
        #pragma unroll
        for (int nt = 0; nt < 8; nt++)
            acc[rt][nt] = (f32x4){0.f, 0.f, 0.f, 0.f};
    __syncthreads();
    #pragma unroll
    for (int kc = 0; kc < 4; kc++){
        const int koff = kc * 32 + qd * 8;
        half8 ahi[2], alo[2];
        const float* px[2] = {X + (size_t)r0 * DD + koff, X + (size_t)r1 * DD + koff};
        #pragma unroll
        for (int rt = 0; rt < 2; rt++){
            float4 v0 = *(const float4*)(px[rt]);
            float4 v1 = *(const float4*)(px[rt] + 4);
            float xv[8] = {v0.x, v0.y, v0.z, v0.w, v1.x, v1.y, v1.z, v1.w};
            #pragma unroll
            for (int j = 0; j < 8; j++){
                _Float16 h = (_Float16)xv[j];
                ahi[rt][j] = h;
                alo[rt][j] = (_Float16)(xv[j] - (float)h);
            }
        }
        #pragma unroll
        for (int nt = 0; nt < 8; nt++){
            const int fi = (((kc << 3) + nt) << 6 | lane) << 3;
            half8 bh = *(const half8*)&sB[0][fi];
            half8 bl = *(const half8*)&sB[1][fi];
            #pragma unroll
            for (int rt = 0; rt < 2; rt++){
                acc[rt][nt] = __builtin_amdgcn_mfma_f32_16x16x32_f16(ahi[rt], bh, acc[rt][nt], 0, 0, 0);
                acc[rt][nt] = __builtin_amdgcn_mfma_f32_16x16x32_f16(alo[rt], bh, acc[rt][nt], 0, 0, 0);
                acc[rt][nt] = __builtin_amdgcn_mfma_f32_16x16x32_f16(ahi[rt], bl, acc[rt][nt], 0, 0, 0);
            }
        }
    }
    #pragma unroll
    for (int nt = 0; nt < 8; nt++){
        const int col = nt * 16 + ln16;
        const float bv = b[col];
        #pragma unroll
        for (int rt = 0; rt < 2; rt++){
            #pragma unroll
            for (int r = 0; r < 4; r++){
                int row = row0 + rt * 16 + qd * 4 + r;
                if (row < nrows){
                    float y = acc[rt][nt][r] + bv;
                    Yb[(size_t)row * DD + col] = h2u((_Float16)y);
                }
            }
        }
    }
}

// Final linear (in-place capable, fp32 in/out): Y = lrelu(X @ W + b)
__global__ __launch_bounds__(256) void lin_mfma(const float* X,
        const unsigned short* Whi, const unsigned short* Wlo, const float* b,
        float* Y, int nrows){
    __shared__ unsigned short sB[2][16384];
    const int tid = threadIdx.x;
    {
        const uint4* gh = (const uint4*)Whi;
        const uint4* gl = (const uint4*)Wlo;
        uint4* lh = (uint4*)sB[0];
        uint4* ll = (uint4*)sB[1];
        #pragma unroll
        for (int t = 0; t < 8; t++){
            lh[tid + 256 * t] = gh[tid + 256 * t];
            ll[tid + 256 * t] = gl[tid + 256 * t];
        }
    }
    const int wave = tid >> 6, lane = tid & 63;
    const int qd = lane >> 4, ln16 = lane & 15;
    const int row0 = blockIdx.x * 128 + wave * 32;
    int r0 = row0 + ln16;       if (r0 >= nrows) r0 = nrows - 1;
    int r1 = row0 + 16 + ln16;  if (r1 >= nrows) r1 = nrows - 1;
    f32x4 acc[2][8];
    #pragma unroll
    for (int rt = 0; rt < 2; rt++)
        #pragma unroll
        for (int nt = 0; nt < 8; nt++)
            acc[rt][nt] = (f32x4){0.f, 0.f, 0.f, 0.f};
    __syncthreads();
    #pragma unroll
    for (int kc = 0; kc < 4; kc++){
        const int koff = kc * 32 + qd * 8;
        half8 ahi[2], alo[2];
        const float* px[2] = {X + (size_t)r0 * DD + koff, X + (size_t)r1 * DD + koff};
        #pragma unroll
        for (int rt = 0; rt < 2; rt++){
            float4 v0 = *(const float4*)(px[rt]);
            float4 v1 = *(const float4*)(px[rt] + 4);
            float xv[8] = {v0.x, v0.y, v0.z, v0.w, v1.x, v1.y, v1.z, v1.w};
            #pragma unroll
            for (int j = 0; j < 8; j++){
                _Float16 h = (_Float16)xv[j];
                ahi[rt][j] = h;
                alo[rt][j] = (_Float16)(xv[j] - (float)h);
            }
        }
        #pragma unroll
        for (int nt = 0; nt < 8; nt++){
            const int fi = (((kc << 3) + nt) << 6 | lane) << 3;
            half8 bh = *(const half8*)&sB[0][fi];
            half8 bl = *(const half8*)&sB[1][fi];
            #pragma unroll
            for (int rt = 0; rt < 2; rt++){
                acc[rt][nt] = __builtin_amdgcn_mfma_f32_16x16x32_f16(ahi[rt], bh, acc[rt][nt], 0, 0, 0);
                acc[rt][nt] = __builtin_amdgcn_mfma_f32_16x16x32_f16(alo[rt], bh, acc[rt][nt], 0, 0, 0);
                acc[rt][nt] = __builtin_amdgcn_mfma_f32_16x16x32_f16(ahi[rt], bl, acc[rt][nt], 0, 0, 0);
            }
        }
    }
    #pragma unroll
    for (int nt = 0; nt < 8; nt++){
        const int col = nt * 16 + ln16;
        const float bv = b[col];
        #pragma unroll
        for (int rt = 0; rt < 2; rt++){
            #pragma unroll
            for (int r = 0; r < 4; r++){
                int row = row0 + rt * 16 + qd * 4 + r;
                if (row < nrows){
                    float y = acc[rt][nt][r] + bv;
                    Y[(size_t)row * DD + col] = lrelu(y);
                }
            }
        }
    }
}

// A-fragment: 8 fp16 of lrelu(hs_row + hd_row) — packed fp16 math, no repack
__device__ __forceinline__ half8 make_afrag(const unsigned short* ph, const unsigned short* pd){
    half8 a = *(const half8*)ph;
    half8 b = *(const half8*)pd;
    half8 s = a + b;                      // v_pk_add_f16 x4
    half8 l = s * (_Float16)0.01f;        // v_pk_mul_f16 x4
    half8 r;
    #pragma unroll
    for (int i = 0; i < 8; i++) r[i] = (s[i] > (_Float16)0.f) ? s[i] : l[i];
    return r;
}

// MFMA edge attention score on SORTED edges; 256 edges/block (2 tiles of 128).
// rt-serialized; writes w = exp(score) directly (softmax shift cancels).
__global__ __launch_bounds__(256) void edge_score_mfma(
        const unsigned short* hs_h, const unsigned short* hd_h,
        const int2* pairs,
        const unsigned short* wa1p, const float* ba1,
        const float* Wa2, const float* ba2,
        float* s_w, int E){
    __shared__ unsigned short sB[16384];  // 32 KB
    const int tid = threadIdx.x;
    {
        const uint4* g = (const uint4*)wa1p;
        uint4* l = (uint4*)sB;
        #pragma unroll
        for (int t = 0; t < 8; t++) l[tid + 256 * t] = g[tid + 256 * t];
    }
    const int wave = tid >> 6, lane = tid & 63;
    const int qd = lane >> 4, ln16 = lane & 15;
    float b1v[8], w2v[8];
    #pragma unroll
    for (int nt = 0; nt < 8; nt++){
        b1v[nt] = ba1[nt * 16 + ln16];
        w2v[nt] = Wa2[nt * 16 + ln16];
    }
    const float b2 = ba2[0];
    __syncthreads();
    for (int half = 0; half < 2; half++){
        const int e0 = blockIdx.x * 256 + half * 128 + wave * 32;
        for (int rt = 0; rt < 2; rt++){
            int eid = e0 + rt * 16 + ln16;
            if (eid >= E) eid = E - 1;
            const int2 pp = pairs[eid];
            f32x4 acc[8];
            #pragma unroll
            for (int nt = 0; nt < 8; nt++) acc[nt] = (f32x4){0.f, 0.f, 0.f, 0.f};
            #pragma unroll
            for (int kc = 0; kc < 4; kc++){
                const int koff = kc * 32 + qd * 8;
                half8 af = make_afrag(hs_h + (size_t)pp.x * DD + koff,
                                      hd_h + (size_t)pp.y * DD + koff);
                #pragma unroll
                for (int nt = 0; nt < 8; nt++){
                    half8 bf = *(const half8*)&sB[(((kc << 3) + nt) << 6 | lane) << 3];
                    acc[nt] = __builtin_amdgcn_mfma_f32_16x16x32_f16(af, bf, acc[nt], 0, 0, 0);
                }
            }
            float p[4] = {0.f, 0.f, 0.f, 0.f};
            #pragma unroll
            for (int nt = 0; nt < 8; nt++)
                #pragma unroll
                for (int r = 0; r < 4; r++){
                    float z = acc[nt][r] + b1v[nt];
                    z = z > 0.f ? z : NEG * z;
                    p[r] += z * w2v[nt];
                }
            #pragma unroll
            for (int r = 0; r < 4; r++){
                float v = p[r];
                #pragma unroll
                for (int off = 1; off < 16; off <<= 1) v += __shfl_xor(v, off, 64);
                p[r] = expf(v + b2);
            }
            if (ln16 == 0){
                int row = e0 + rt * 16 + qd * 4;
                #pragma unroll
                for (int r = 0; r < 4; r++)
                    if (row + r < E) s_w[row + r] = p[r];
            }
        }
    }
}

// one wave per dst node, single pass:
// nf[n] = (sum_e w_e * hs[src_e]) / (sum_e w_e) + hd[n]
__global__ __launch_bounds__(256) void agg_softmax(const unsigned short* hs_h,
        const unsigned short* hd_h, const int* row_off, const int* s_srcs,
        const float* s_w, float* nf, int n_dst){
    const int w = (blockIdx.x * blockDim.x + threadIdx.x) >> 6;
    const int lane = threadIdx.x & 63;
    if (w >= n_dst) return;
    const int beg = row_off[w], end = row_off[w + 1];
    float2 acc = make_float2(0.f, 0.f);
    float sa = 0.f;
    int e = beg;
    for (; e + 3 < end; e += 4){
        float w0 = s_w[e], w1 = s_w[e + 1], w2 = s_w[e + 2], w3 = s_w[e + 3];
        int s0 = s_srcs[e], s1 = s_srcs[e + 1], s2 = s_srcs[e + 2], s3 = s_srcs[e + 3];
        ushort2 u0 = *(const ushort2*)(hs_h + (size_t)s0 * DD + lane * 2);
        ushort2 u1 = *(const ushort2*)(hs_h + (size_t)s1 * DD + lane * 2);
        ushort2 u2 = *(const ushort2*)(hs_h + (size_t)s2 * DD + lane * 2);
        ushort2 u3 = *(const ushort2*)(hs_h + (size_t)s3 * DD + lane * 2);
        acc.x += w0 * (float)u2h(u0.x) + w1 * (float)u2h(u1.x)
               + w2 * (float)u2h(u2.x) + w3 * (float)u2h(u3.x);
        acc.y += w0 * (float)u2h(u0.y) + w1 * (float)u2h(u1.y)
               + w2 * (float)u2h(u2.y) + w3 * (float)u2h(u3.y);
        sa += (w0 + w1) + (w2 + w3);
    }
    for (; e < end; e++){
        float w0 = s_w[e];
        int s0 = s_srcs[e];
        ushort2 u0 = *(const ushort2*)(hs_h + (size_t)s0 * DD + lane * 2);
        acc.x += w0 * (float)u2h(u0.x);
        acc.y += w0 * (float)u2h(u0.y);
        sa += w0;
    }
    const float inv = (end > beg) ? 1.f / sa : 0.f;
    ushort2 hu = *(const ushort2*)(hd_h + (size_t)w * DD + lane * 2);
    const float hx = (end > beg) ? (float)u2h(hu.x) : 0.f;
    const float hy = (end > beg) ? (float)u2h(hu.y) : 0.f;
    float2 out;
    out.x = acc.x * inv + hx;
    out.y = acc.y * inv + hy;
    *(float2*)(nf + (size_t)w * DD + lane * 2) = out;
}

extern "C" void kernel_launch(void* const* d_in, const int* in_sizes, int n_in,
                              void* d_out, int out_size, void* d_ws, size_t ws_size,
                              hipStream_t stream){
    const float* feat_src = (const float*)d_in[0];
    const float* feat_dst = (const float*)d_in[1];
    const int*   src_idx  = (const int*)d_in[2];
    const int*   dst_idx  = (const int*)d_in[3];
    const float* W_src = (const float*)d_in[4];
    const float* b_src = (const float*)d_in[5];
    const float* W_dst = (const float*)d_in[6];
    const float* b_dst = (const float*)d_in[7];
    const float* W_a1  = (const float*)d_in[8];
    const float* b_a1  = (const float*)d_in[9];
    const float* W_a2  = (const float*)d_in[10];
    const float* b_a2  = (const float*)d_in[11];
    const float* W_out = (const float*)d_in[12];
    const float* b_out = (const float*)d_in[13];
    const int n_src = in_sizes[0] / DD;
    const int n_dst = in_sizes[1] / DD;
    const int E = in_sizes[2];
    const int nchunks = (n_dst + SCHUNK - 1) / SCHUNK;

    // workspace layout (all 16B-aligned segments)
    char* p = (char*)d_ws;
    unsigned short* hs_h = (unsigned short*)p;  p += (size_t)n_src * DD * 2;
    unsigned short* hd_h = (unsigned short*)p;  p += (size_t)n_dst * DD * 2;
    unsigned short* wpack = (unsigned short*)p; p += 7 * 16384 * 2;
    float* s_w = (float*)p;                     p += (size_t)E * 4;
    int2* pairs = (int2*)p;                     p += (size_t)E * 8;
    int* s_srcs = (int*)p;                      p += (size_t)E * 4;
    int* deg = (int*)p;                         p += (size_t)n_dst * 4;
    int* cursor = (int*)p;                      p += (size_t)n_dst * 4;
    int* part = (int*)p;                        p += 64 * 4;
    int* row_off = (int*)p;                     p += ((size_t)n_dst + 1) * 4;
    float* nf = (float*)d_out;

    const unsigned short* wa1p    = wpack;
    const unsigned short* wsrc_hi = wpack + 1 * 16384;
    const unsigned short* wsrc_lo = wpack + 2 * 16384;
    const unsigned short* wdst_hi = wpack + 3 * 16384;
    const unsigned short* wdst_lo = wpack + 4 * 16384;
    const unsigned short* wout_hi = wpack + 5 * 16384;
    const unsigned short* wout_lo = wpack + 6 * 16384;

    hipMemsetAsync(deg, 0, (size_t)n_dst * 4, stream);
    const int nhist = (E + 255) / 256;
    const int npack = (7 * 16384 + 255) / 256;
    hist_pack<<<nhist + npack, 256, 0, stream>>>(dst_idx, deg, E, nhist,
                                                 W_a1, W_src, W_dst, W_out, wpack);
    scan1<<<nchunks, 1024, 0, stream>>>(deg, part, n_dst);
    scan2<<<nchunks, 1024, 0, stream>>>(deg, part, row_off, cursor, n_dst, nchunks);
    scatter_pairs<<<(E + 255) / 256, 256, 0, stream>>>(src_idx, dst_idx, cursor,
                                                       pairs, s_srcs, E);
    const int g1 = (n_src + 127) / 128;
    const int g2 = (n_dst + 127) / 128;
    lin2_mfma<<<g1 + g2, 256, 0, stream>>>(feat_src, wsrc_hi, wsrc_lo, b_src, hs_h, n_src, g1,
                                           feat_dst, wdst_hi, wdst_lo, b_dst, hd_h, n_dst);
    edge_score_mfma<<<(E + 255) / 256, 256, 0, stream>>>(hs_h, hd_h, pairs, wa1p, b_a1,
                                                         W_a2, b_a2, s_w, E);
    agg_softmax<<<((size_t)n_dst * 64 + 255) / 256, 256, 0, stream>>>(hs_h, hd_h, row_off,
                                                                      s_srcs, s_w, nf, n_dst);
    lin_mfma<<<g2, 256, 0, stream>>>(nf, wout_hi, wout_lo, b_out, nf, n_dst);
}

// Round 9
// 315.032 us; speedup vs baseline: 1.2529x; 1.0317x over previous
//
#include <hip/hip_runtime.h>
#include <math.h>

#define DD 128
#define NEG 0.01f
#define SCHUNK 4096

typedef __attribute__((ext_vector_type(8))) _Float16 half8;
typedef __attribute__((ext_vector_type(4))) float f32x4;

__device__ __forceinline__ float lrelu(float x){ return x > 0.f ? x : NEG * x; }

__device__ __forceinline__ unsigned short h2u(_Float16 h){
    union { _Float16 h; unsigned short u; } v; v.h = h; return v.u;
}
__device__ __forceinline__ _Float16 u2h(unsigned short u){
    union { unsigned short u; _Float16 h; } v; v.u = u; return v.h;
}

// histogram + fp16 weight pack fused (disjoint block ranges)
// wpack segs: 0 Wa1, 1 Wsrc, 2 Wdst, 3 Wout — MFMA B-fragment-linear order
__global__ void hist_pack(const int* dst, int* deg, int E, int nhist,
                          const float* Wa1, const float* Wsrc,
                          const float* Wdst, const float* Wout,
                          unsigned short* wpack){
    const int bid = blockIdx.x;
    if (bid < nhist){
        int i = bid * 256 + threadIdx.x;
        if (i < E) atomicAdd(&deg[dst[i]], 1);
    } else {
        int i = (bid - nhist) * 256 + threadIdx.x;   // [0, 4*16384)
        if (i >= 4 * 16384) return;
        int seg = i >> 14, t = i & 16383;
        int j = t & 7, lane = (t >> 3) & 63, nt = (t >> 9) & 7, kc = t >> 12;
        int k = kc * 32 + (lane >> 4) * 8 + j;
        int n = nt * 16 + (lane & 15);
        const float* W = (seg == 0) ? Wa1 : (seg == 1) ? Wsrc : (seg == 2) ? Wdst : Wout;
        wpack[i] = h2u((_Float16)W[k * DD + n]);
    }
}

// two-level scan, level 1: per-chunk sums (chunk = 4096 ints)
__global__ __launch_bounds__(1024) void scan1(const int* deg, int* part, int n){
    __shared__ int wsum[16];
    const int tid = threadIdx.x;
    const int lane = tid & 63, wid = tid >> 6;
    int i4 = blockIdx.x * SCHUNK + tid * 4;
    int4 v = make_int4(0, 0, 0, 0);
    if (i4 + 3 < n) v = *(const int4*)(deg + i4);
    else {
        if (i4 + 0 < n) v.x = deg[i4 + 0];
        if (i4 + 1 < n) v.y = deg[i4 + 1];
        if (i4 + 2 < n) v.z = deg[i4 + 2];
        if (i4 + 3 < n) v.w = deg[i4 + 3];
    }
    int t = v.x + v.y + v.z + v.w;
    #pragma unroll
    for (int off = 1; off < 64; off <<= 1) t += __shfl_xor(t, off, 64);
    if (lane == 0) wsum[wid] = t;
    __syncthreads();
    if (tid == 0){
        int s = 0;
        #pragma unroll
        for (int j = 0; j < 16; j++) s += wsum[j];
        part[blockIdx.x] = s;
    }
}

// two-level scan, level 2: exclusive offsets + cursor copy
__global__ __launch_bounds__(1024) void scan2(const int* deg, const int* part,
        int* row_off, int* cursor, int n, int nchunks){
    __shared__ int wsum[16];
    const int tid = threadIdx.x;
    const int lane = tid & 63, wid = tid >> 6;
    const int b = blockIdx.x;
    int carry = 0;
    for (int j = 0; j < b; j++) carry += part[j];
    int i4 = b * SCHUNK + tid * 4;
    int4 v = make_int4(0, 0, 0, 0);
    if (i4 + 3 < n) v = *(const int4*)(deg + i4);
    else {
        if (i4 + 0 < n) v.x = deg[i4 + 0];
        if (i4 + 1 < n) v.y = deg[i4 + 1];
        if (i4 + 2 < n) v.z = deg[i4 + 2];
        if (i4 + 3 < n) v.w = deg[i4 + 3];
    }
    int tsum = v.x + v.y + v.z + v.w;
    int x = tsum;
    #pragma unroll
    for (int off = 1; off < 64; off <<= 1){
        int t = __shfl_up(x, off, 64);
        if (lane >= off) x += t;
    }
    if (lane == 63) wsum[wid] = x;
    __syncthreads();
    int wprefix = 0;
    #pragma unroll
    for (int j = 0; j < 16; j++) if (j < wid) wprefix += wsum[j];
    int excl = carry + wprefix + (x - tsum);
    if (i4 + 3 < n){
        int4 o;
        o.x = excl; o.y = excl + v.x; o.z = o.y + v.y; o.w = o.z + v.z;
        *(int4*)(row_off + i4) = o;
        *(int4*)(cursor + i4) = o;
    } else {
        int a = excl;
        if (i4 + 0 < n){ row_off[i4 + 0] = a; cursor[i4 + 0] = a; a += v.x; }
        if (i4 + 1 < n){ row_off[i4 + 1] = a; cursor[i4 + 1] = a; a += v.y; }
        if (i4 + 2 < n){ row_off[i4 + 2] = a; cursor[i4 + 2] = a; a += v.z; }
        if (i4 + 3 < n){ row_off[i4 + 3] = a; cursor[i4 + 3] = a; }
    }
    if (b == 0 && tid == 0){
        int tot = 0;
        for (int j = 0; j < nchunks; j++) tot += part[j];
        row_off[n] = tot;
    }
}

// bucket edges by dst: sorted (src,dst) pairs in CSR order + SoA src copy
__global__ void scatter_pairs(const int* src, const int* dst, int* cursor,
                              int2* pairs, int* s_srcs, int E){
    int i = blockIdx.x * blockDim.x + threadIdx.x;
    if (i < E){
        int d = dst[i];
        int s = src[i];
        int pos = atomicAdd(&cursor[d], 1);
        pairs[pos] = make_int2(s, d);
        s_srcs[pos] = s;
    }
}

// Node linear via single fp16 MFMA (~1e-3 abs accuracy, sufficient).
// Y[r] = X[r] @ W + b (fp16 out). 128 rows/block (4 waves x 32 rows).
// Fused: blocks [0,g1): (X1,W1,b1)->Yb1; blocks [g1,..): (X2,W2,b2)->Yb2.
__global__ __launch_bounds__(256) void lin2_mfma(
        const float* X1, const unsigned short* W1, const float* b1,
        unsigned short* Yb1, int n1, int g1,
        const float* X2, const unsigned short* W2, const float* b2,
        unsigned short* Yb2, int n2){
    __shared__ unsigned short sB[16384];   // 32 KB
    const int tid = threadIdx.x;
    const int second = (blockIdx.x >= g1);
    const float* X = second ? X2 : X1;
    const unsigned short* W = second ? W2 : W1;
    const float* b = second ? b2 : b1;
    unsigned short* Yb = second ? Yb2 : Yb1;
    const int nrows = second ? n2 : n1;
    const int bidx = second ? (blockIdx.x - g1) : blockIdx.x;
    {
        const uint4* g = (const uint4*)W;
        uint4* l = (uint4*)sB;
        #pragma unroll
        for (int t = 0; t < 8; t++) l[tid + 256 * t] = g[tid + 256 * t];
    }
    const int wave = tid >> 6, lane = tid & 63;
    const int qd = lane >> 4, ln16 = lane & 15;
    const int row0 = bidx * 128 + wave * 32;
    int r0 = row0 + ln16;       if (r0 >= nrows) r0 = nrows - 1;
    int r1 = row0 + 16 + ln16;  if (r1 >= nrows) r1 = nrows - 1;
    f32x4 acc[2][8];
    #pragma unroll
    for (int rt = 0; rt < 2; rt++)
        #pragma unroll
        for (int nt = 0; nt < 8; nt++)
            acc[rt][nt] = (f32x4){0.f, 0.f, 0.f, 0.f};
    __syncthreads();
    #pragma unroll
    for (int kc = 0; kc < 4; kc++){
        const int koff = kc * 32 + qd * 8;
        half8 a[2];
        const float* px[2] = {X + (size_t)r0 * DD + koff, X + (size_t)r1 * DD + koff};
        #pragma unroll
        for (int rt = 0; rt < 2; rt++){
            float4 v0 = *(const float4*)(px[rt]);
            float4 v1 = *(const float4*)(px[rt] + 4);
            a[rt][0] = (_Float16)v0.x; a[rt][1] = (_Float16)v0.y;
            a[rt][2] = (_Float16)v0.z; a[rt][3] = (_Float16)v0.w;
            a[rt][4] = (_Float16)v1.x; a[rt][5] = (_Float16)v1.y;
            a[rt][6] = (_Float16)v1.z; a[rt][7] = (_Float16)v1.w;
        }
        #pragma unroll
        for (int nt = 0; nt < 8; nt++){
            const int fi = (((kc << 3) + nt) << 6 | lane) << 3;
            half8 bw = *(const half8*)&sB[fi];
            acc[0][nt] = __builtin_amdgcn_mfma_f32_16x16x32_f16(a[0], bw, acc[0][nt], 0, 0, 0);
            acc[1][nt] = __builtin_amdgcn_mfma_f32_16x16x32_f16(a[1], bw, acc[1][nt], 0, 0, 0);
        }
    }
    #pragma unroll
    for (int nt = 0; nt < 8; nt++){
        const int col = nt * 16 + ln16;
        const float bv = b[col];
        #pragma unroll
        for (int rt = 0; rt < 2; rt++){
            #pragma unroll
            for (int r = 0; r < 4; r++){
                int row = row0 + rt * 16 + qd * 4 + r;
                if (row < nrows){
                    float y = acc[rt][nt][r] + bv;
                    Yb[(size_t)row * DD + col] = h2u((_Float16)y);
                }
            }
        }
    }
}

// Final linear (fp32 in/out, in-place): Y = lrelu(X @ W + b)
__global__ __launch_bounds__(256) void lin_mfma(const float* X,
        const unsigned short* W, const float* b, float* Y, int nrows){
    __shared__ unsigned short sB[16384];
    const int tid = threadIdx.x;
    {
        const uint4* g = (const uint4*)W;
        uint4* l = (uint4*)sB;
        #pragma unroll
        for (int t = 0; t < 8; t++) l[tid + 256 * t] = g[tid + 256 * t];
    }
    const int wave = tid >> 6, lane = tid & 63;
    const int qd = lane >> 4, ln16 = lane & 15;
    const int row0 = blockIdx.x * 128 + wave * 32;
    int r0 = row0 + ln16;       if (r0 >= nrows) r0 = nrows - 1;
    int r1 = row0 + 16 + ln16;  if (r1 >= nrows) r1 = nrows - 1;
    f32x4 acc[2][8];
    #pragma unroll
    for (int rt = 0; rt < 2; rt++)
        #pragma unroll
        for (int nt = 0; nt < 8; nt++)
            acc[rt][nt] = (f32x4){0.f, 0.f, 0.f, 0.f};
    __syncthreads();
    #pragma unroll
    for (int kc = 0; kc < 4; kc++){
        const int koff = kc * 32 + qd * 8;
        half8 a[2];
        const float* px[2] = {X + (size_t)r0 * DD + koff, X + (size_t)r1 * DD + koff};
        #pragma unroll
        for (int rt = 0; rt < 2; rt++){
            float4 v0 = *(const float4*)(px[rt]);
            float4 v1 = *(const float4*)(px[rt] + 4);
            a[rt][0] = (_Float16)v0.x; a[rt][1] = (_Float16)v0.y;
            a[rt][2] = (_Float16)v0.z; a[rt][3] = (_Float16)v0.w;
            a[rt][4] = (_Float16)v1.x; a[rt][5] = (_Float16)v1.y;
            a[rt][6] = (_Float16)v1.z; a[rt][7] = (_Float16)v1.w;
        }
        #pragma unroll
        for (int nt = 0; nt < 8; nt++){
            const int fi = (((kc << 3) + nt) << 6 | lane) << 3;
            half8 bw = *(const half8*)&sB[fi];
            acc[0][nt] = __builtin_amdgcn_mfma_f32_16x16x32_f16(a[0], bw, acc[0][nt], 0, 0, 0);
            acc[1][nt] = __builtin_amdgcn_mfma_f32_16x16x32_f16(a[1], bw, acc[1][nt], 0, 0, 0);
        }
    }
    #pragma unroll
    for (int nt = 0; nt < 8; nt++){
        const int col = nt * 16 + ln16;
        const float bv = b[col];
        #pragma unroll
        for (int rt = 0; rt < 2; rt++){
            #pragma unroll
            for (int r = 0; r < 4; r++){
                int row = row0 + rt * 16 + qd * 4 + r;
                if (row < nrows){
                    float y = acc[rt][nt][r] + bv;
                    Y[(size_t)row * DD + col] = lrelu(y);
                }
            }
        }
    }
}

// A-fragment: 8 fp16 of lrelu(hs_row + hd_row) — packed fp16 math
__device__ __forceinline__ half8 make_afrag(const unsigned short* ph, const unsigned short* pd){
    half8 a = *(const half8*)ph;
    half8 b = *(const half8*)pd;
    half8 s = a + b;
    half8 l = s * (_Float16)0.01f;
    half8 r;
    #pragma unroll
    for (int i = 0; i < 8; i++) r[i] = (s[i] > (_Float16)0.f) ? s[i] : l[i];
    return r;
}

// MFMA edge attention score on SORTED edges; 128 edges/block.
// rt-serialized (8 f32x4 acc live); writes w = exp(score) directly.
__global__ __launch_bounds__(256) void edge_score_mfma(
        const unsigned short* hs_h, const unsigned short* hd_h,
        const int2* pairs,
        const unsigned short* wa1p, const float* ba1,
        const float* Wa2, const float* ba2,
        float* s_w, int E){
    __shared__ unsigned short sB[16384];  // 32 KB
    const int tid = threadIdx.x;
    {
        const uint4* g = (const uint4*)wa1p;
        uint4* l = (uint4*)sB;
        #pragma unroll
        for (int t = 0; t < 8; t++) l[tid + 256 * t] = g[tid + 256 * t];
    }
    const int wave = tid >> 6, lane = tid & 63;
    const int qd = lane >> 4, ln16 = lane & 15;
    const int e0 = blockIdx.x * 128 + wave * 32;
    float b1v[8], w2v[8];
    #pragma unroll
    for (int nt = 0; nt < 8; nt++){
        b1v[nt] = ba1[nt * 16 + ln16];
        w2v[nt] = Wa2[nt * 16 + ln16];
    }
    const float b2 = ba2[0];
    __syncthreads();
    for (int rt = 0; rt < 2; rt++){
        int eid = e0 + rt * 16 + ln16;
        if (eid >= E) eid = E - 1;
        const int2 pp = pairs[eid];
        f32x4 acc[8];
        #pragma unroll
        for (int nt = 0; nt < 8; nt++) acc[nt] = (f32x4){0.f, 0.f, 0.f, 0.f};
        #pragma unroll
        for (int kc = 0; kc < 4; kc++){
            const int koff = kc * 32 + qd * 8;
            half8 af = make_afrag(hs_h + (size_t)pp.x * DD + koff,
                                  hd_h + (size_t)pp.y * DD + koff);
            #pragma unroll
            for (int nt = 0; nt < 8; nt++){
                half8 bf = *(const half8*)&sB[(((kc << 3) + nt) << 6 | lane) << 3];
                acc[nt] = __builtin_amdgcn_mfma_f32_16x16x32_f16(af, bf, acc[nt], 0, 0, 0);
            }
        }
        float p[4] = {0.f, 0.f, 0.f, 0.f};
        #pragma unroll
        for (int nt = 0; nt < 8; nt++)
            #pragma unroll
            for (int r = 0; r < 4; r++){
                float z = acc[nt][r] + b1v[nt];
                z = z > 0.f ? z : NEG * z;
                p[r] += z * w2v[nt];
            }
        #pragma unroll
        for (int r = 0; r < 4; r++){
            float v = p[r];
            #pragma unroll
            for (int off = 1; off < 16; off <<= 1) v += __shfl_xor(v, off, 64);
            p[r] = expf(v + b2);
        }
        if (ln16 == 0){
            int row = e0 + rt * 16 + qd * 4;
            #pragma unroll
            for (int r = 0; r < 4; r++)
                if (row + r < E) s_w[row + r] = p[r];
        }
    }
}

// one wave per dst node, single pass (8-edge unroll for MLP):
// nf[n] = (sum_e w_e * hs[src_e]) / (sum_e w_e) + hd[n]
__global__ __launch_bounds__(256) void agg_softmax(const unsigned short* hs_h,
        const unsigned short* hd_h, const int* row_off, const int* s_srcs,
        const float* s_w, float* nf, int n_dst){
    const int w = (blockIdx.x * blockDim.x + threadIdx.x) >> 6;
    const int lane = threadIdx.x & 63;
    if (w >= n_dst) return;
    const int beg = row_off[w], end = row_off[w + 1];
    float2 acc = make_float2(0.f, 0.f);
    float sa = 0.f;
    int e = beg;
    for (; e + 7 < end; e += 8){
        float wv[8]; int sv[8]; ushort2 uv[8];
        #pragma unroll
        for (int j = 0; j < 8; j++){ wv[j] = s_w[e + j]; sv[j] = s_srcs[e + j]; }
        #pragma unroll
        for (int j = 0; j < 8; j++)
            uv[j] = *(const ushort2*)(hs_h + (size_t)sv[j] * DD + lane * 2);
        #pragma unroll
        for (int j = 0; j < 8; j++){
            acc.x += wv[j] * (float)u2h(uv[j].x);
            acc.y += wv[j] * (float)u2h(uv[j].y);
            sa += wv[j];
        }
    }
    for (; e < end; e++){
        float w0 = s_w[e];
        int s0 = s_srcs[e];
        ushort2 u0 = *(const ushort2*)(hs_h + (size_t)s0 * DD + lane * 2);
        acc.x += w0 * (float)u2h(u0.x);
        acc.y += w0 * (float)u2h(u0.y);
        sa += w0;
    }
    const float inv = (end > beg) ? 1.f / sa : 0.f;
    ushort2 hu = *(const ushort2*)(hd_h + (size_t)w * DD + lane * 2);
    const float hx = (end > beg) ? (float)u2h(hu.x) : 0.f;
    const float hy = (end > beg) ? (float)u2h(hu.y) : 0.f;
    float2 out;
    out.x = acc.x * inv + hx;
    out.y = acc.y * inv + hy;
    *(float2*)(nf + (size_t)w * DD + lane * 2) = out;
}

extern "C" void kernel_launch(void* const* d_in, const int* in_sizes, int n_in,
                              void* d_out, int out_size, void* d_ws, size_t ws_size,
                              hipStream_t stream){
    const float* feat_src = (const float*)d_in[0];
    const float* feat_dst = (const float*)d_in[1];
    const int*   src_idx  = (const int*)d_in[2];
    const int*   dst_idx  = (const int*)d_in[3];
    const float* W_src = (const float*)d_in[4];
    const float* b_src = (const float*)d_in[5];
    const float* W_dst = (const float*)d_in[6];
    const float* b_dst = (const float*)d_in[7];
    const float* W_a1  = (const float*)d_in[8];
    const float* b_a1  = (const float*)d_in[9];
    const float* W_a2  = (const float*)d_in[10];
    const float* b_a2  = (const float*)d_in[11];
    const float* W_out = (const float*)d_in[12];
    const float* b_out = (const float*)d_in[13];
    const int n_src = in_sizes[0] / DD;
    const int n_dst = in_sizes[1] / DD;
    const int E = in_sizes[2];
    const int nchunks = (n_dst + SCHUNK - 1) / SCHUNK;

    // workspace layout (all 16B-aligned segments)
    char* p = (char*)d_ws;
    unsigned short* hs_h = (unsigned short*)p;  p += (size_t)n_src * DD * 2;
    unsigned short* hd_h = (unsigned short*)p;  p += (size_t)n_dst * DD * 2;
    unsigned short* wpack = (unsigned short*)p; p += 4 * 16384 * 2;
    float* s_w = (float*)p;                     p += (size_t)E * 4;
    int2* pairs = (int2*)p;                     p += (size_t)E * 8;
    int* s_srcs = (int*)p;                      p += (size_t)E * 4;
    int* deg = (int*)p;                         p += (size_t)n_dst * 4;
    int* cursor = (int*)p;                      p += (size_t)n_dst * 4;
    int* part = (int*)p;                        p += 64 * 4;
    int* row_off = (int*)p;                     p += ((size_t)n_dst + 1) * 4;
    float* nf = (float*)d_out;

    const unsigned short* wa1p = wpack;
    const unsigned short* wsrc = wpack + 1 * 16384;
    const unsigned short* wdst = wpack + 2 * 16384;
    const unsigned short* wout = wpack + 3 * 16384;

    hipMemsetAsync(deg, 0, (size_t)n_dst * 4, stream);
    const int nhist = (E + 255) / 256;
    const int npack = (4 * 16384 + 255) / 256;
    hist_pack<<<nhist + npack, 256, 0, stream>>>(dst_idx, deg, E, nhist,
                                                 W_a1, W_src, W_dst, W_out, wpack);
    scan1<<<nchunks, 1024, 0, stream>>>(deg, part, n_dst);
    scan2<<<nchunks, 1024, 0, stream>>>(deg, part, row_off, cursor, n_dst, nchunks);
    scatter_pairs<<<(E + 255) / 256, 256, 0, stream>>>(src_idx, dst_idx, cursor,
                                                       pairs, s_srcs, E);
    const int g1 = (n_src + 127) / 128;
    const int g2 = (n_dst + 127) / 128;
    lin2_mfma<<<g1 + g2, 256, 0, stream>>>(feat_src, wsrc, b_src, hs_h, n_src, g1,
                                           feat_dst, wdst, b_dst, hd_h, n_dst);
    edge_score_mfma<<<(E + 127) / 128, 256, 0, stream>>>(hs_h, hd_h, pairs, wa1p, b_a1,
                                                         W_a2, b_a2, s_w, E);
    agg_softmax<<<((size_t)n_dst * 64 + 255) / 256, 256, 0, stream>>>(hs_h, hd_h, row_off,
                                                                      s_srcs, s_w, nf, n_dst);
    lin_mfma<<<g2, 256, 0, stream>>>(nf, wout, b_out, nf, n_dst);
}